// Round 1
// baseline (489.829 us; speedup 1.0000x reference)
//
#include <hip/hip_runtime.h>
#include <hip/hip_bf16.h>
#include <math.h>

// B=2, L=4, C=128, H=W=96. Only fusion target i=0 is consumed downstream.
#define HW 9216
#define CC 128

// ---------------- theta setup: 8 (b,j) affine matrices ----------------
// M = tm[b,j,0] (rows 0..1, cols 0,1,3 of P; translation /1.6)
// T = [R | center - R@center + t]; A = n@[T;0 0 1]@inv(n) collapses to
// A = [[T00,T01,T00+T01-1+(2/95)T02],[T10,T11,T10+T11-1+(2/95)T12]]
// theta = inv(A)[:2,:]
__global__ void k_theta(const float* __restrict__ P, float* __restrict__ th) {
    int t = threadIdx.x;
    if (t >= 8) return;
    int b = t >> 2, j = t & 3;
    const float* M = P + (size_t)(b * 4 + j) * 64;  // [l'=0][r][c], r stride 4
    float a00 = M[0], a01 = M[1], a02 = M[3] / 1.6f;
    float a10 = M[4], a11 = M[5], a12 = M[7] / 1.6f;
    const float cx = 48.f, cy = 48.f;
    float T02 = cx - (a00 * cx + a01 * cy) + a02;
    float T12 = cy - (a10 * cx + a11 * cy) + a12;
    float A02 = a00 + a01 - 1.f + (2.f / 95.f) * T02;
    float A12 = a10 + a11 - 1.f + (2.f / 95.f) * T12;
    float det = a00 * a11 - a01 * a10;
    float i00 = a11 / det, i01 = -a01 / det, i10 = -a10 / det, i11 = a00 / det;
    float* o = th + t * 6;
    o[0] = i00; o[1] = i01; o[2] = -(i00 * A02 + i01 * A12);
    o[3] = i10; o[4] = i11; o[5] = -(i10 * A02 + i11 * A12);
}

// ---------------- transpose x -> channel-last xT[bn][y][x][c] ----------------
__global__ __launch_bounds__(256) void k_transpose(const float* __restrict__ x, float* __restrict__ xT) {
    int bn = blockIdx.x / 96, y = blockIdx.x % 96;
    __shared__ float tile[96][129];
    const float* src = x + (size_t)bn * 128 * HW + (size_t)y * 96;
    for (int i = threadIdx.x; i < 128 * 96; i += 256) {
        int c = i / 96, xx = i - c * 96;
        tile[xx][c] = src[(size_t)c * HW + xx];
    }
    __syncthreads();
    float* dst = xT + ((size_t)bn * 96 + y) * 96 * 128;
    for (int i = threadIdx.x; i < 96 * 128; i += 256) {
        int xx = i >> 7, c = i & 127;
        dst[i] = tile[xx][c];
    }
}

// ---------------- per-channel variance of agent-0 feats (ddof=1) ----------------
__global__ __launch_bounds__(256) void k_var(const float* __restrict__ x, float* __restrict__ var) {
    int b = blockIdx.x >> 7, c = blockIdx.x & 127;
    const float* src = x + ((size_t)(b * 4) * 128 + c) * HW;
    float s = 0.f, ss = 0.f;
    for (int i = threadIdx.x; i < HW; i += 256) { float v = src[i]; s += v; ss += v * v; }
    __shared__ float rs[256], rss[256];
    rs[threadIdx.x] = s; rss[threadIdx.x] = ss; __syncthreads();
    for (int o = 128; o > 0; o >>= 1) {
        if (threadIdx.x < o) { rs[threadIdx.x] += rs[threadIdx.x + o]; rss[threadIdx.x] += rss[threadIdx.x + o]; }
        __syncthreads();
    }
    if (threadIdx.x == 0) {
        float mean = rs[0] / 9216.f;
        var[b * 128 + c] = (rss[0] - 9216.f * mean * mean) / 9215.f;
    }
}

__global__ void k_argmax(const float* __restrict__ var, int* __restrict__ cmax) {
    int b = blockIdx.x, t = threadIdx.x;
    __shared__ float v[128]; __shared__ int idx[128];
    v[t] = var[b * 128 + t]; idx[t] = t; __syncthreads();
    for (int o = 64; o > 0; o >>= 1) {
        if (t < o) { if (v[t + o] > v[t]) { v[t] = v[t + o]; idx[t] = idx[t + o]; } }
        __syncthreads();
    }
    if (t == 0) cmax[b] = idx[0];
}

// ---------------- gather: sel[b][j][p][c], ego[b][p][c], roi[b][j][p] ----------------
__global__ __launch_bounds__(256) void k_gather(const float* __restrict__ xT, const float* __restrict__ th,
                                                const int* __restrict__ cmax, float* __restrict__ sel,
                                                float* __restrict__ ego, float* __restrict__ roi) {
    int blk = blockIdx.x;
    int bj = blk / 4608, pblk = blk - bj * 4608;
    int b = bj >> 2, j = bj & 3;
    int pr = threadIdx.x >> 7, c = threadIdx.x & 127;
    int p = pblk * 2 + pr;
    int h = p / 96, w = p - h * 96;
    const float* t6 = th + bj * 6;
    float X = -1.f + (2.f / 95.f) * (float)w, Y = -1.f + (2.f / 95.f) * (float)h;
    float gx = t6[0] * X + t6[1] * Y + t6[2];
    float gy = t6[3] * X + t6[4] * Y + t6[5];
    float px = (gx + 1.f) * 47.5f, py = (gy + 1.f) * 47.5f;
    float x0f = floorf(px), y0f = floorf(py);
    float wx = px - x0f, wy = py - y0f;
    int x0 = (int)x0f, y0 = (int)y0f, x1 = x0 + 1, y1 = y0 + 1;
    float w00 = (1.f - wx) * (1.f - wy), w10 = wx * (1.f - wy);
    float w01 = (1.f - wx) * wy, w11 = wx * wy;
    bool vx0 = (x0 >= 0) && (x0 <= 95), vx1 = (x1 >= 0) && (x1 <= 95);
    bool vy0 = (y0 >= 0) && (y0 <= 95), vy1 = (y1 >= 0) && (y1 <= 95);
    float f00 = (vx0 && vy0) ? w00 : 0.f, f10 = (vx1 && vy0) ? w10 : 0.f;
    float f01 = (vx0 && vy1) ? w01 : 0.f, f11 = (vx1 && vy1) ? w11 : 0.f;
    int xc0 = min(max(x0, 0), 95), xc1 = min(max(x1, 0), 95);
    int yc0 = min(max(y0, 0), 95), yc1 = min(max(y1, 0), 95);
    const float* base = xT + (size_t)bj * HW * CC;
    // sample of flipped image: value(xi,yi) = feats[b,j,c,95-xi,yi] = xT[bj][95-xi][yi][c]
    float nb = f00 * base[((95 - xc0) * 96 + yc0) * CC + c]
             + f10 * base[((95 - xc1) * 96 + yc0) * CC + c]
             + f01 * base[((95 - xc0) * 96 + yc1) * CC + c]
             + f11 * base[((95 - xc1) * 96 + yc1) * CC + c];
    const float* ebase = xT + (size_t)(b * 4) * HW * CC;
    float egov = ebase[((95 - w) * 96 + h) * CC + c];
    float sv = (b == 0) ? nb : ((c == cmax[b]) ? nb : egov);
    sel[((size_t)bj * HW + p) * CC + c] = sv;
    if (j == 0) ego[((size_t)b * HW + p) * CC + c] = egov;
    if (c == 0) roi[(size_t)bj * HW + p] = f00 + f10 + f01 + f11;
}

// ---------------- per-pixel MLP (256->128->32->8->1) -> logits ----------------
// 64 pixels/block, 4 waves; wave ty owns a contiguous output slice; weights are
// wave-uniform scalar loads (readfirstlane).
__global__ __launch_bounds__(256) void k_mlp(const float* __restrict__ sel, const float* __restrict__ ego,
        const float* __restrict__ w1, const float* __restrict__ b1, const float* __restrict__ s1, const float* __restrict__ t1,
        const float* __restrict__ w2, const float* __restrict__ b2, const float* __restrict__ s2, const float* __restrict__ t2,
        const float* __restrict__ w3, const float* __restrict__ b3, const float* __restrict__ s3, const float* __restrict__ t3,
        const float* __restrict__ w4, const float* __restrict__ b4, float* __restrict__ logi) {
    extern __shared__ float sm[];
    float* Xs  = sm;             // [256][65]
    float* l1s = sm + 256 * 65;  // [128][65]
    float* l2s = sm;             // [32][65]  (reuses Xs after layer1)
    float* l3s = sm + 32 * 65;   // [8][65]
    int blk = blockIdx.x;
    int bj = blk / 144, pt = blk - bj * 144;
    int b = bj >> 2;
    int p0 = pt * 64;
    const float* selp = sel + ((size_t)bj * HW + p0) * CC;
    const float* egop = ego + ((size_t)b * HW + p0) * CC;
    for (int i = threadIdx.x; i < 64 * 128; i += 256) {
        int pp = i >> 7, k = i & 127;
        Xs[k * 65 + pp] = selp[i];
        Xs[(128 + k) * 65 + pp] = egop[i];
    }
    __syncthreads();
    int lane = threadIdx.x & 63;
    int tyu = __builtin_amdgcn_readfirstlane(threadIdx.x >> 6);
    // layer 1
    float acc[32];
    #pragma unroll
    for (int i = 0; i < 32; i++) acc[i] = 0.f;
    {
        const float* wr = w1 + (size_t)tyu * 32 * 256;
        for (int kc = 0; kc < 256; kc += 8) {
            float xr[8];
            #pragma unroll
            for (int kk = 0; kk < 8; kk++) xr[kk] = Xs[(kc + kk) * 65 + lane];
            #pragma unroll
            for (int i = 0; i < 32; i++) {
                #pragma unroll
                for (int kk = 0; kk < 8; kk++) acc[i] += xr[kk] * wr[i * 256 + kc + kk];
            }
        }
    }
    #pragma unroll
    for (int i = 0; i < 32; i++) {
        int o = tyu * 32 + i;
        float v = (acc[i] + b1[o]) * s1[o] + t1[o];
        l1s[o * 65 + lane] = fmaxf(v, 0.f);
    }
    __syncthreads();
    // layer 2
    float a2[8];
    #pragma unroll
    for (int i = 0; i < 8; i++) a2[i] = 0.f;
    {
        const float* wr = w2 + (size_t)tyu * 8 * 128;
        for (int kc = 0; kc < 128; kc += 8) {
            float xr[8];
            #pragma unroll
            for (int kk = 0; kk < 8; kk++) xr[kk] = l1s[(kc + kk) * 65 + lane];
            #pragma unroll
            for (int i = 0; i < 8; i++) {
                #pragma unroll
                for (int kk = 0; kk < 8; kk++) a2[i] += xr[kk] * wr[i * 128 + kc + kk];
            }
        }
    }
    #pragma unroll
    for (int i = 0; i < 8; i++) {
        int o = tyu * 8 + i;
        float v = (a2[i] + b2[o]) * s2[o] + t2[o];
        l2s[o * 65 + lane] = fmaxf(v, 0.f);
    }
    __syncthreads();
    // layer 3
    float a3[2] = {0.f, 0.f};
    #pragma unroll
    for (int k = 0; k < 32; k++) {
        float xv = l2s[k * 65 + lane];
        a3[0] += xv * w3[(tyu * 2 + 0) * 32 + k];
        a3[1] += xv * w3[(tyu * 2 + 1) * 32 + k];
    }
    #pragma unroll
    for (int i = 0; i < 2; i++) {
        int o = tyu * 2 + i;
        float v = (a3[i] + b3[o]) * s3[o] + t3[o];
        l3s[o * 65 + lane] = fmaxf(v, 0.f);
    }
    __syncthreads();
    // layer 4 (relu!)
    if (tyu == 0) {
        float s = b4[0];
        #pragma unroll
        for (int k = 0; k < 8; k++) s += w4[k] * l3s[k * 65 + lane];
        logi[(size_t)bj * HW + p0 + lane] = fmaxf(s, 0.f);
    }
}

// ---------------- softmax over sources + weighted combine ----------------
__global__ __launch_bounds__(256) void k_combine(const float* __restrict__ sel, const float* __restrict__ roi,
                                                 const float* __restrict__ logi, float* __restrict__ fused) {
    int blk = blockIdx.x;
    int b = blk / 4608;
    int p = (blk - b * 4608) * 2 + (threadIdx.x >> 7);
    int c = threadIdx.x & 127;
    float lg[4], rr[4];
    #pragma unroll
    for (int j = 0; j < 4; j++) {
        rr[j] = roi[(size_t)(b * 4 + j) * HW + p];
        lg[j] = logi[(size_t)(b * 4 + j) * HW + p];
    }
    float m = -1e30f;
    #pragma unroll
    for (int j = 0; j < 4; j++) if (rr[j] != 0.f && lg[j] > m) m = lg[j];
    float e[4], se = 0.f;
    #pragma unroll
    for (int j = 0; j < 4; j++) { e[j] = (rr[j] != 0.f) ? expf(lg[j] - m) : 0.f; se += e[j]; }
    float inv = 1.f / se;
    float acc = 0.f;
    #pragma unroll
    for (int j = 0; j < 4; j++) {
        float sv = sel[((size_t)(b * 4 + j) * HW + p) * CC + c];
        acc += (e[j] * inv) * rr[j] * sv;
    }
    fused[((size_t)b * HW + p) * CC + c] = acc;
}

// ---------------- final per-pixel 128x128 MLP + un-flip writeback ----------------
__global__ __launch_bounds__(256) void k_out(const float* __restrict__ fused, const float* __restrict__ mw,
                                             const float* __restrict__ mb, float* __restrict__ out) {
    int blk = blockIdx.x;
    int b = blk / 144, pt = blk - b * 144;
    int p0 = pt * 64;
    __shared__ float Xs[128 * 65];
    const float* fp = fused + ((size_t)b * HW + p0) * CC;
    for (int i = threadIdx.x; i < 64 * 128; i += 256) {
        int pp = i >> 7, c = i & 127;
        Xs[c * 65 + pp] = fp[i];
    }
    __syncthreads();
    int lane = threadIdx.x & 63;
    int tyu = __builtin_amdgcn_readfirstlane(threadIdx.x >> 6);
    float acc[32];
    #pragma unroll
    for (int i = 0; i < 32; i++) acc[i] = 0.f;
    const float* wr = mw + (size_t)tyu * 32 * 128;
    for (int kc = 0; kc < 128; kc += 8) {
        float xr[8];
        #pragma unroll
        for (int kk = 0; kk < 8; kk++) xr[kk] = Xs[(kc + kk) * 65 + lane];
        #pragma unroll
        for (int i = 0; i < 32; i++) {
            #pragma unroll
            for (int kk = 0; kk < 8; kk++) acc[i] += xr[kk] * wr[i * 128 + kc + kk];
        }
    }
    int p = p0 + lane;
    int h = p / 96, w = p - h * 96;
    float* op = out + (((size_t)b * 96 + (95 - w)) * 96 + h) * CC + tyu * 32;
    #pragma unroll
    for (int i = 0; i < 32; i++) op[i] = acc[i] + mb[tyu * 32 + i];
}

extern "C" void kernel_launch(void* const* d_in, const int* in_sizes, int n_in,
                              void* d_out, int out_size, void* d_ws, size_t ws_size,
                              hipStream_t stream) {
    const float* x  = (const float*)d_in[0];
    const float* P  = (const float*)d_in[2];
    const float* w1 = (const float*)d_in[3];
    const float* b1 = (const float*)d_in[4];
    const float* s1 = (const float*)d_in[5];
    const float* t1 = (const float*)d_in[6];
    const float* w2 = (const float*)d_in[7];
    const float* b2 = (const float*)d_in[8];
    const float* s2 = (const float*)d_in[9];
    const float* t2 = (const float*)d_in[10];
    const float* w3 = (const float*)d_in[11];
    const float* b3 = (const float*)d_in[12];
    const float* s3 = (const float*)d_in[13];
    const float* t3 = (const float*)d_in[14];
    const float* w4 = (const float*)d_in[15];
    const float* b4 = (const float*)d_in[16];
    const float* mw = (const float*)d_in[17];
    const float* mb = (const float*)d_in[18];
    float* out = (float*)d_out;

    float* ws   = (float*)d_ws;
    float* TH   = ws;                    // 48
    float* VAR  = ws + 64;               // 256
    int*   CMX  = (int*)(ws + 320);      // 2
    float* XT   = ws + 384;              // 2*4*96*96*128 = 9437184
    float* SEL  = XT + 9437184;          // 9437184
    float* EGO  = SEL + 9437184;         // 2359296
    float* ROI  = EGO + 2359296;         // 73728
    float* LOGI = ROI + 73728;           // 73728
    float* FUS  = XT;                    // reuse XT after gather

    k_theta<<<1, 64, 0, stream>>>(P, TH);
    k_transpose<<<768, 256, 0, stream>>>(x, XT);
    k_var<<<256, 256, 0, stream>>>(x, VAR);
    k_argmax<<<2, 128, 0, stream>>>(VAR, CMX);
    k_gather<<<36864, 256, 0, stream>>>(XT, TH, CMX, SEL, EGO, ROI);
    k_mlp<<<1152, 256, 99840, stream>>>(SEL, EGO, w1, b1, s1, t1, w2, b2, s2, t2,
                                        w3, b3, s3, t3, w4, b4, LOGI);
    k_combine<<<9216, 256, 0, stream>>>(SEL, ROI, LOGI, FUS);
    k_out<<<288, 256, 0, stream>>>(FUS, mw, mb, out);
}

// Round 2
// 231.944 us; speedup vs baseline: 2.1118x; 2.1118x over previous
//
#include <hip/hip_runtime.h>
#include <hip/hip_bf16.h>
#include <math.h>

// B=2, L=4, C=128, H=W=96. Only fusion target i=0 is consumed downstream.
#define HW 9216
#define CC 128

typedef __attribute__((ext_vector_type(4))) float f32x4;
typedef __attribute__((ext_vector_type(8))) short s16x8;

static __device__ __forceinline__ unsigned short f2bf(float f) {
    __hip_bfloat16 h = __float2bfloat16(f);
    return *reinterpret_cast<unsigned short*>(&h);
}

// ---------------- theta setup: 8 (b,j) affine matrices ----------------
__global__ void k_theta(const float* __restrict__ P, float* __restrict__ th) {
    int t = threadIdx.x;
    if (t >= 8) return;
    int b = t >> 2, j = t & 3;
    const float* M = P + (size_t)(b * 4 + j) * 64;
    float a00 = M[0], a01 = M[1], a02 = M[3] / 1.6f;
    float a10 = M[4], a11 = M[5], a12 = M[7] / 1.6f;
    const float cx = 48.f, cy = 48.f;
    float T02 = cx - (a00 * cx + a01 * cy) + a02;
    float T12 = cy - (a10 * cx + a11 * cy) + a12;
    float A02 = a00 + a01 - 1.f + (2.f / 95.f) * T02;
    float A12 = a10 + a11 - 1.f + (2.f / 95.f) * T12;
    float det = a00 * a11 - a01 * a10;
    float i00 = a11 / det, i01 = -a01 / det, i10 = -a10 / det, i11 = a00 / det;
    float* o = th + t * 6;
    o[0] = i00; o[1] = i01; o[2] = -(i00 * A02 + i01 * A12);
    o[3] = i10; o[4] = i11; o[5] = -(i10 * A02 + i11 * A12);
}

// ---------------- convert w1,w2 to bf16 tables ----------------
__global__ __launch_bounds__(256) void k_wcvt(const float* __restrict__ w1, const float* __restrict__ w2,
                                              unsigned short* __restrict__ w1b, unsigned short* __restrict__ w2b) {
    int t = blockIdx.x * 256 + threadIdx.x;
    for (int i = t; i < 32768; i += gridDim.x * 256) w1b[i] = f2bf(w1[i]);
    if (t < 4096) w2b[t] = f2bf(w2[t]);
}

// ---------------- transpose x -> channel-last xT[bn][y][x][c] ----------------
__global__ __launch_bounds__(256) void k_transpose(const float* __restrict__ x, float* __restrict__ xT) {
    int bn = blockIdx.x / 96, y = blockIdx.x % 96;
    __shared__ float tile[96][129];
    const float* src = x + (size_t)bn * 128 * HW + (size_t)y * 96;
    for (int i = threadIdx.x; i < 128 * 96; i += 256) {
        int c = i / 96, xx = i - c * 96;
        tile[xx][c] = src[(size_t)c * HW + xx];
    }
    __syncthreads();
    float* dst = xT + ((size_t)bn * 96 + y) * 96 * 128;
    for (int i = threadIdx.x; i < 96 * 128; i += 256) {
        int xx = i >> 7, c = i & 127;
        dst[i] = tile[xx][c];
    }
}

// ---------------- per-channel variance of agent-0 feats (ddof=1) ----------------
__global__ __launch_bounds__(256) void k_var(const float* __restrict__ x, float* __restrict__ var) {
    int b = blockIdx.x >> 7, c = blockIdx.x & 127;
    const float* src = x + ((size_t)(b * 4) * 128 + c) * HW;
    float s = 0.f, ss = 0.f;
    for (int i = threadIdx.x; i < HW; i += 256) { float v = src[i]; s += v; ss += v * v; }
    __shared__ float rs[256], rss[256];
    rs[threadIdx.x] = s; rss[threadIdx.x] = ss; __syncthreads();
    for (int o = 128; o > 0; o >>= 1) {
        if (threadIdx.x < o) { rs[threadIdx.x] += rs[threadIdx.x + o]; rss[threadIdx.x] += rss[threadIdx.x + o]; }
        __syncthreads();
    }
    if (threadIdx.x == 0) {
        float mean = rs[0] / 9216.f;
        var[b * 128 + c] = (rss[0] - 9216.f * mean * mean) / 9215.f;
    }
}

__global__ void k_argmax(const float* __restrict__ var, int* __restrict__ cmax) {
    int b = blockIdx.x, t = threadIdx.x;
    __shared__ float v[128]; __shared__ int idx[128];
    v[t] = var[b * 128 + t]; idx[t] = t; __syncthreads();
    for (int o = 64; o > 0; o >>= 1) {
        if (t < o) { if (v[t + o] > v[t]) { v[t] = v[t + o]; idx[t] = idx[t + o]; } }
        __syncthreads();
    }
    if (t == 0) cmax[b] = idx[0];
}

// ---------------- gather: sel[b][j][p][c], ego[b][p][c], roi[b][j][p] ----------------
// 16 px per block.
__global__ __launch_bounds__(256) void k_gather(const float* __restrict__ xT, const float* __restrict__ th,
                                                const int* __restrict__ cmax, float* __restrict__ sel,
                                                float* __restrict__ ego, float* __restrict__ roi) {
    int blk = blockIdx.x;
    int bj = blk / 576, pblk = blk - bj * 576;
    int b = bj >> 2, j = bj & 3;
    int pr = threadIdx.x >> 7, c = threadIdx.x & 127;
    const float* t6 = th + bj * 6;
    float T0 = t6[0], T1 = t6[1], T2 = t6[2], T3 = t6[3], T4 = t6[4], T5 = t6[5];
    int cm = cmax[b];
    const float* base = xT + (size_t)bj * HW * CC;
    const float* ebase = xT + (size_t)(b * 4) * HW * CC;
    #pragma unroll
    for (int it = 0; it < 8; it++) {
        int p = pblk * 16 + it * 2 + pr;
        int h = p / 96, w = p - h * 96;
        float X = -1.f + (2.f / 95.f) * (float)w, Y = -1.f + (2.f / 95.f) * (float)h;
        float gx = T0 * X + T1 * Y + T2;
        float gy = T3 * X + T4 * Y + T5;
        float px = (gx + 1.f) * 47.5f, py = (gy + 1.f) * 47.5f;
        float x0f = floorf(px), y0f = floorf(py);
        float wx = px - x0f, wy = py - y0f;
        int x0 = (int)x0f, y0 = (int)y0f, x1 = x0 + 1, y1 = y0 + 1;
        float w00 = (1.f - wx) * (1.f - wy), w10 = wx * (1.f - wy);
        float w01 = (1.f - wx) * wy, w11 = wx * wy;
        bool vx0 = (x0 >= 0) && (x0 <= 95), vx1 = (x1 >= 0) && (x1 <= 95);
        bool vy0 = (y0 >= 0) && (y0 <= 95), vy1 = (y1 >= 0) && (y1 <= 95);
        float f00 = (vx0 && vy0) ? w00 : 0.f, f10 = (vx1 && vy0) ? w10 : 0.f;
        float f01 = (vx0 && vy1) ? w01 : 0.f, f11 = (vx1 && vy1) ? w11 : 0.f;
        int xc0 = min(max(x0, 0), 95), xc1 = min(max(x1, 0), 95);
        int yc0 = min(max(y0, 0), 95), yc1 = min(max(y1, 0), 95);
        float nb = f00 * base[((95 - xc0) * 96 + yc0) * CC + c]
                 + f10 * base[((95 - xc1) * 96 + yc0) * CC + c]
                 + f01 * base[((95 - xc0) * 96 + yc1) * CC + c]
                 + f11 * base[((95 - xc1) * 96 + yc1) * CC + c];
        float egov = ebase[((95 - w) * 96 + h) * CC + c];
        float sv = (b == 0) ? nb : ((c == cm) ? nb : egov);
        sel[((size_t)bj * HW + p) * CC + c] = sv;
        if (j == 0) ego[((size_t)b * HW + p) * CC + c] = egov;
        if (c == 0) roi[(size_t)bj * HW + p] = f00 + f10 + f01 + f11;
    }
}

// ---------------- per-pixel MLP via bf16 MFMA: 256->128->32->8->1 ----------------
// block = 256 thr (4 waves), 64 pixels. LDS 32KB. Wave w owns output quarter
// [w*32, w*32+32) in GEMM1 and M-tile px [w*16,+16) in GEMM2.
__global__ __launch_bounds__(256, 4) void k_mlp(
    const float* __restrict__ sel, const float* __restrict__ ego,
    const unsigned short* __restrict__ w1b, const unsigned short* __restrict__ w2b,
    const float* __restrict__ b1, const float* __restrict__ s1, const float* __restrict__ t1,
    const float* __restrict__ b2, const float* __restrict__ s2, const float* __restrict__ t2,
    const float* __restrict__ w3, const float* __restrict__ b3, const float* __restrict__ s3,
    const float* __restrict__ t3, const float* __restrict__ w4, const float* __restrict__ b4,
    float* __restrict__ logi) {
    __shared__ __align__(16) unsigned char sm[32768];
    int t = threadIdx.x;
    int blk = blockIdx.x;
    int bj = blk / 144, pt = blk - bj * 144;
    int b = bj >> 2;
    int p0 = pt * 64;
    const float* selp = sel + ((size_t)bj * HW + p0) * CC;
    const float* egop = ego + ((size_t)b * HW + p0) * CC;
    // ---- stage X = [sel || ego] as bf16 [64px][256k], XOR-swizzled (T2) ----
    #pragma unroll 4
    for (int it = 0; it < 32; it++) {
        int i = t + it * 256;
        int px = i >> 7, kp = i & 127;
        float2 v;
        if (kp < 64) v = *(const float2*)(selp + px * 128 + kp * 2);
        else         v = *(const float2*)(egop + px * 128 + (kp - 64) * 2);
        unsigned int pk = (unsigned int)f2bf(v.x) | ((unsigned int)f2bf(v.y) << 16);
        int kb = kp * 4;  // byte offset of element pair (2k with k=2*kp)
        *(unsigned int*)(sm + px * 512 + (kb ^ ((px & 7) << 4))) = pk;
    }
    int lane = t & 63;
    int w = t >> 6;
    int l15 = lane & 15;
    int l4 = lane >> 4;
    // layer-1 affine params (vector loads, lane&15-indexed, L2-hot)
    float bb[2], ss[2], tt[2];
    #pragma unroll
    for (int nt = 0; nt < 2; nt++) {
        int o = w * 32 + nt * 16 + l15;
        bb[nt] = b1[o]; ss[nt] = s1[o]; tt[nt] = t1[o];
    }
    __syncthreads();
    // ---- GEMM1: C[64px][32out(this wave)] = X[64][256] @ W1^T ----
    f32x4 acc[4][2];
    #pragma unroll
    for (int mt = 0; mt < 4; mt++)
        #pragma unroll
        for (int nt = 0; nt < 2; nt++) acc[mt][nt] = f32x4{0.f, 0.f, 0.f, 0.f};
    const unsigned short* wb = w1b + (size_t)(w * 32) * 256;
    s16x8 bcur[2], bnxt[2];
    #pragma unroll
    for (int nt = 0; nt < 2; nt++)
        bcur[nt] = *(const s16x8*)(wb + (nt * 16 + l15) * 256 + l4 * 8);
    #pragma unroll
    for (int kt = 0; kt < 8; kt++) {
        if (kt < 7) {
            #pragma unroll
            for (int nt = 0; nt < 2; nt++)
                bnxt[nt] = *(const s16x8*)(wb + (nt * 16 + l15) * 256 + (kt + 1) * 32 + l4 * 8);
        }
        int k0 = kt * 32 + l4 * 8;
        #pragma unroll
        for (int mt = 0; mt < 4; mt++) {
            int px = mt * 16 + l15;
            s16x8 af = *(const s16x8*)(sm + px * 512 + ((2 * k0) ^ ((px & 7) << 4)));
            #pragma unroll
            for (int nt = 0; nt < 2; nt++)
                acc[mt][nt] = __builtin_amdgcn_mfma_f32_16x16x32_bf16(af, bcur[nt], acc[mt][nt], 0, 0, 0);
        }
        #pragma unroll
        for (int nt = 0; nt < 2; nt++) bcur[nt] = bnxt[nt];
    }
    __syncthreads();  // all waves done reading Xs
    // ---- epilogue1: affine+relu -> L1s bf16 [64px][128] swizzled (overlays Xs) ----
    #pragma unroll
    for (int mt = 0; mt < 4; mt++) {
        #pragma unroll
        for (int nt = 0; nt < 2; nt++) {
            int o = w * 32 + nt * 16 + l15;
            #pragma unroll
            for (int r = 0; r < 4; r++) {
                int px = mt * 16 + l4 * 4 + r;
                float v = (acc[mt][nt][r] + bb[nt]) * ss[nt] + tt[nt];
                v = fmaxf(v, 0.f);
                *(unsigned short*)(sm + px * 256 + ((2 * o) ^ ((px & 7) << 4))) = f2bf(v);
            }
        }
    }
    __syncthreads();
    // ---- GEMM2: C[16px(this wave)][32out] = L1[16][128] @ W2^T ----
    f32x4 acc2[2];
    acc2[0] = f32x4{0.f, 0.f, 0.f, 0.f};
    acc2[1] = f32x4{0.f, 0.f, 0.f, 0.f};
    s16x8 b2f[2][4];
    #pragma unroll
    for (int nt = 0; nt < 2; nt++)
        #pragma unroll
        for (int kt = 0; kt < 4; kt++)
            b2f[nt][kt] = *(const s16x8*)(w2b + (nt * 16 + l15) * 128 + kt * 32 + l4 * 8);
    #pragma unroll
    for (int kt = 0; kt < 4; kt++) {
        int px = w * 16 + l15;
        int k0 = kt * 32 + l4 * 8;
        s16x8 af = *(const s16x8*)(sm + px * 256 + ((2 * k0) ^ ((px & 7) << 4)));
        #pragma unroll
        for (int nt = 0; nt < 2; nt++)
            acc2[nt] = __builtin_amdgcn_mfma_f32_16x16x32_bf16(af, b2f[nt][kt], acc2[nt], 0, 0, 0);
    }
    // ---- epilogue2: affine+relu -> L2s f32 [64px][37] at byte 16384 (disjoint) ----
    float* l2s = (float*)(sm + 16384);
    #pragma unroll
    for (int nt = 0; nt < 2; nt++) {
        int o = nt * 16 + l15;
        float b2v = b2[o], s2v = s2[o], t2v = t2[o];
        #pragma unroll
        for (int r = 0; r < 4; r++) {
            int px = w * 16 + l4 * 4 + r;
            float v = (acc2[nt][r] + b2v) * s2v + t2v;
            l2s[px * 37 + o] = fmaxf(v, 0.f);
        }
    }
    __syncthreads();
    // ---- layers 3+4 (fp32 VALU, wave 0): 32->8->1 + relu -> logits ----
    if (t < 64) {
        int px = t;
        float xv[32];
        #pragma unroll
        for (int k = 0; k < 32; k++) xv[k] = l2s[px * 37 + k];
        float lg = b4[0];
        #pragma unroll
        for (int o = 0; o < 8; o++) {
            float a = 0.f;
            #pragma unroll
            for (int k = 0; k < 32; k++) a += xv[k] * w3[o * 32 + k];
            float l3v = fmaxf((a + b3[o]) * s3[o] + t3[o], 0.f);
            lg += w4[o] * l3v;
        }
        logi[(size_t)bj * HW + p0 + px] = fmaxf(lg, 0.f);
    }
}

// ---------------- softmax over sources + weighted combine (8 px/block) ----------------
__global__ __launch_bounds__(256) void k_combine(const float* __restrict__ sel, const float* __restrict__ roi,
                                                 const float* __restrict__ logi, float* __restrict__ fused) {
    int blk = blockIdx.x;
    int b = blk / 1152, pblk = blk - b * 1152;
    int pr = threadIdx.x >> 7, c = threadIdx.x & 127;
    #pragma unroll
    for (int it = 0; it < 4; it++) {
        int p = pblk * 8 + it * 2 + pr;
        float lg[4], rr[4];
        #pragma unroll
        for (int j = 0; j < 4; j++) {
            rr[j] = roi[(size_t)(b * 4 + j) * HW + p];
            lg[j] = logi[(size_t)(b * 4 + j) * HW + p];
        }
        float m = -1e30f;
        #pragma unroll
        for (int j = 0; j < 4; j++) if (rr[j] != 0.f && lg[j] > m) m = lg[j];
        float e[4], se = 0.f;
        #pragma unroll
        for (int j = 0; j < 4; j++) { e[j] = (rr[j] != 0.f) ? expf(lg[j] - m) : 0.f; se += e[j]; }
        float inv = 1.f / se;
        float acc = 0.f;
        #pragma unroll
        for (int j = 0; j < 4; j++) {
            float sv = sel[((size_t)(b * 4 + j) * HW + p) * CC + c];
            acc += (e[j] * inv) * rr[j] * sv;
        }
        fused[((size_t)b * HW + p) * CC + c] = acc;
    }
}

// ---------------- final per-pixel 128x128 MLP + un-flip writeback ----------------
__global__ __launch_bounds__(256) void k_out(const float* __restrict__ fused, const float* __restrict__ mw,
                                             const float* __restrict__ mb, float* __restrict__ out) {
    int blk = blockIdx.x;
    int b = blk / 144, pt = blk - b * 144;
    int p0 = pt * 64;
    __shared__ float Xs[128 * 65];
    const float* fp = fused + ((size_t)b * HW + p0) * CC;
    for (int i = threadIdx.x; i < 64 * 128; i += 256) {
        int pp = i >> 7, c = i & 127;
        Xs[c * 65 + pp] = fp[i];
    }
    __syncthreads();
    int lane = threadIdx.x & 63;
    int tyu = __builtin_amdgcn_readfirstlane(threadIdx.x >> 6);
    float acc[32];
    #pragma unroll
    for (int i = 0; i < 32; i++) acc[i] = 0.f;
    const float* wr = mw + (size_t)tyu * 32 * 128;
    for (int kc = 0; kc < 128; kc += 8) {
        float xr[8];
        #pragma unroll
        for (int kk = 0; kk < 8; kk++) xr[kk] = Xs[(kc + kk) * 65 + lane];
        #pragma unroll
        for (int i = 0; i < 32; i++) {
            #pragma unroll
            for (int kk = 0; kk < 8; kk++) acc[i] += xr[kk] * wr[i * 128 + kc + kk];
        }
    }
    int p = p0 + lane;
    int h = p / 96, w = p - h * 96;
    float* op = out + (((size_t)b * 96 + (95 - w)) * 96 + h) * CC + tyu * 32;
    #pragma unroll
    for (int i = 0; i < 32; i++) op[i] = acc[i] + mb[tyu * 32 + i];
}

extern "C" void kernel_launch(void* const* d_in, const int* in_sizes, int n_in,
                              void* d_out, int out_size, void* d_ws, size_t ws_size,
                              hipStream_t stream) {
    const float* x  = (const float*)d_in[0];
    const float* P  = (const float*)d_in[2];
    const float* w1 = (const float*)d_in[3];
    const float* b1 = (const float*)d_in[4];
    const float* s1 = (const float*)d_in[5];
    const float* t1 = (const float*)d_in[6];
    const float* w2 = (const float*)d_in[7];
    const float* b2 = (const float*)d_in[8];
    const float* s2 = (const float*)d_in[9];
    const float* t2 = (const float*)d_in[10];
    const float* w3 = (const float*)d_in[11];
    const float* b3 = (const float*)d_in[12];
    const float* s3 = (const float*)d_in[13];
    const float* t3 = (const float*)d_in[14];
    const float* w4 = (const float*)d_in[15];
    const float* b4 = (const float*)d_in[16];
    const float* mw = (const float*)d_in[17];
    const float* mb = (const float*)d_in[18];
    float* out = (float*)d_out;

    float* ws   = (float*)d_ws;
    float* TH   = ws;                    // 48
    float* VAR  = ws + 64;               // 256
    int*   CMX  = (int*)(ws + 320);      // 2
    float* XT   = ws + 384;              // 2*4*96*96*128 = 9437184
    float* SEL  = XT + 9437184;          // 9437184
    float* EGO  = SEL + 9437184;         // 2359296
    float* ROI  = EGO + 2359296;         // 73728
    float* LOGI = ROI + 73728;           // 73728
    unsigned short* W1B = (unsigned short*)(LOGI + 73728);  // 32768 bf16
    unsigned short* W2B = W1B + 32768;                      // 4096 bf16
    float* FUS  = XT;                    // reuse XT after gather

    k_theta<<<1, 64, 0, stream>>>(P, TH);
    k_wcvt<<<32, 256, 0, stream>>>(w1, w2, W1B, W2B);
    k_transpose<<<768, 256, 0, stream>>>(x, XT);
    k_var<<<256, 256, 0, stream>>>(x, VAR);
    k_argmax<<<2, 128, 0, stream>>>(VAR, CMX);
    k_gather<<<4608, 256, 0, stream>>>(XT, TH, CMX, SEL, EGO, ROI);
    k_mlp<<<1152, 256, 0, stream>>>(SEL, EGO, W1B, W2B, b1, s1, t1, b2, s2, t2,
                                    w3, b3, s3, t3, w4, b4, LOGI);
    k_combine<<<2304, 256, 0, stream>>>(SEL, ROI, LOGI, FUS);
    k_out<<<288, 256, 0, stream>>>(FUS, mw, mb, out);
}

// Round 3
// 199.400 us; speedup vs baseline: 2.4565x; 1.1632x over previous
//
#include <hip/hip_runtime.h>
#include <hip/hip_bf16.h>
#include <math.h>

// B=2, L=4, C=128, H=W=96. Only fusion target i=0 is consumed downstream.
#define HW 9216
#define CC 128

typedef __attribute__((ext_vector_type(4))) float f32x4;
typedef __attribute__((ext_vector_type(8))) short s16x8;

static __device__ __forceinline__ unsigned short f2bf(float f) {
    __hip_bfloat16 h = __float2bfloat16(f);
    return *reinterpret_cast<unsigned short*>(&h);
}

// ---------------- theta setup: 8 (b,j) affine matrices ----------------
__global__ void k_theta(const float* __restrict__ P, float* __restrict__ th) {
    int t = threadIdx.x;
    if (t >= 8) return;
    int b = t >> 2, j = t & 3;
    const float* M = P + (size_t)(b * 4 + j) * 64;
    float a00 = M[0], a01 = M[1], a02 = M[3] / 1.6f;
    float a10 = M[4], a11 = M[5], a12 = M[7] / 1.6f;
    const float cx = 48.f, cy = 48.f;
    float T02 = cx - (a00 * cx + a01 * cy) + a02;
    float T12 = cy - (a10 * cx + a11 * cy) + a12;
    float A02 = a00 + a01 - 1.f + (2.f / 95.f) * T02;
    float A12 = a10 + a11 - 1.f + (2.f / 95.f) * T12;
    float det = a00 * a11 - a01 * a10;
    float i00 = a11 / det, i01 = -a01 / det, i10 = -a10 / det, i11 = a00 / det;
    float* o = th + t * 6;
    o[0] = i00; o[1] = i01; o[2] = -(i00 * A02 + i01 * A12);
    o[3] = i10; o[4] = i11; o[5] = -(i10 * A02 + i11 * A12);
}

// ---------------- convert w1,w2,mlp_w to bf16 tables ----------------
__global__ __launch_bounds__(256) void k_wcvt(const float* __restrict__ w1, const float* __restrict__ w2,
                                              const float* __restrict__ mw,
                                              unsigned short* __restrict__ w1b, unsigned short* __restrict__ w2b,
                                              unsigned short* __restrict__ mwb) {
    int t = blockIdx.x * 256 + threadIdx.x;
    int nthr = gridDim.x * 256;
    for (int i = t; i < 32768; i += nthr) w1b[i] = f2bf(w1[i]);
    for (int i = t; i < 16384; i += nthr) mwb[i] = f2bf(mw[i]);
    if (t < 4096) w2b[t] = f2bf(w2[t]);
}

// ---------------- transpose x -> channel-last xT[bn][y][x][c] ----------------
__global__ __launch_bounds__(256) void k_transpose(const float* __restrict__ x, float* __restrict__ xT) {
    int bn = blockIdx.x / 96, y = blockIdx.x % 96;
    __shared__ float tile[96][129];
    const float* src = x + (size_t)bn * 128 * HW + (size_t)y * 96;
    for (int i = threadIdx.x; i < 128 * 96; i += 256) {
        int c = i / 96, xx = i - c * 96;
        tile[xx][c] = src[(size_t)c * HW + xx];
    }
    __syncthreads();
    float* dst = xT + ((size_t)bn * 96 + y) * 96 * 128;
    for (int i = threadIdx.x; i < 96 * 128; i += 256) {
        int xx = i >> 7, c = i & 127;
        dst[i] = tile[xx][c];
    }
}

// ---------------- per-channel variance of agent-0 feats (ddof=1) ----------------
__global__ __launch_bounds__(256) void k_var(const float* __restrict__ x, float* __restrict__ var) {
    int b = blockIdx.x >> 7, c = blockIdx.x & 127;
    const float* src = x + ((size_t)(b * 4) * 128 + c) * HW;
    float s = 0.f, ss = 0.f;
    for (int i = threadIdx.x; i < HW; i += 256) { float v = src[i]; s += v; ss += v * v; }
    __shared__ float rs[256], rss[256];
    rs[threadIdx.x] = s; rss[threadIdx.x] = ss; __syncthreads();
    for (int o = 128; o > 0; o >>= 1) {
        if (threadIdx.x < o) { rs[threadIdx.x] += rs[threadIdx.x + o]; rss[threadIdx.x] += rss[threadIdx.x + o]; }
        __syncthreads();
    }
    if (threadIdx.x == 0) {
        float mean = rs[0] / 9216.f;
        var[b * 128 + c] = (rss[0] - 9216.f * mean * mean) / 9215.f;
    }
}

__global__ void k_argmax(const float* __restrict__ var, int* __restrict__ cmax) {
    int b = blockIdx.x, t = threadIdx.x;
    __shared__ float v[128]; __shared__ int idx[128];
    v[t] = var[b * 128 + t]; idx[t] = t; __syncthreads();
    for (int o = 64; o > 0; o >>= 1) {
        if (t < o) { if (v[t + o] > v[t]) { v[t] = v[t + o]; idx[t] = idx[t + o]; } }
        __syncthreads();
    }
    if (t == 0) cmax[b] = idx[0];
}

// ---------------- gather: sel[b][j][p][c], ego[b][p][c], roi[b][j][p] ----------------
// 16 px per block.
__global__ __launch_bounds__(256) void k_gather(const float* __restrict__ xT, const float* __restrict__ th,
                                                const int* __restrict__ cmax, float* __restrict__ sel,
                                                float* __restrict__ ego, float* __restrict__ roi) {
    int blk = blockIdx.x;
    int bj = blk / 576, pblk = blk - bj * 576;
    int b = bj >> 2, j = bj & 3;
    int pr = threadIdx.x >> 7, c = threadIdx.x & 127;
    const float* t6 = th + bj * 6;
    float T0 = t6[0], T1 = t6[1], T2 = t6[2], T3 = t6[3], T4 = t6[4], T5 = t6[5];
    int cm = cmax[b];
    const float* base = xT + (size_t)bj * HW * CC;
    const float* ebase = xT + (size_t)(b * 4) * HW * CC;
    #pragma unroll
    for (int it = 0; it < 8; it++) {
        int p = pblk * 16 + it * 2 + pr;
        int h = p / 96, w = p - h * 96;
        float X = -1.f + (2.f / 95.f) * (float)w, Y = -1.f + (2.f / 95.f) * (float)h;
        float gx = T0 * X + T1 * Y + T2;
        float gy = T3 * X + T4 * Y + T5;
        float px = (gx + 1.f) * 47.5f, py = (gy + 1.f) * 47.5f;
        float x0f = floorf(px), y0f = floorf(py);
        float wx = px - x0f, wy = py - y0f;
        int x0 = (int)x0f, y0 = (int)y0f, x1 = x0 + 1, y1 = y0 + 1;
        float w00 = (1.f - wx) * (1.f - wy), w10 = wx * (1.f - wy);
        float w01 = (1.f - wx) * wy, w11 = wx * wy;
        bool vx0 = (x0 >= 0) && (x0 <= 95), vx1 = (x1 >= 0) && (x1 <= 95);
        bool vy0 = (y0 >= 0) && (y0 <= 95), vy1 = (y1 >= 0) && (y1 <= 95);
        float f00 = (vx0 && vy0) ? w00 : 0.f, f10 = (vx1 && vy0) ? w10 : 0.f;
        float f01 = (vx0 && vy1) ? w01 : 0.f, f11 = (vx1 && vy1) ? w11 : 0.f;
        int xc0 = min(max(x0, 0), 95), xc1 = min(max(x1, 0), 95);
        int yc0 = min(max(y0, 0), 95), yc1 = min(max(y1, 0), 95);
        float nb = f00 * base[((95 - xc0) * 96 + yc0) * CC + c]
                 + f10 * base[((95 - xc1) * 96 + yc0) * CC + c]
                 + f01 * base[((95 - xc0) * 96 + yc1) * CC + c]
                 + f11 * base[((95 - xc1) * 96 + yc1) * CC + c];
        float egov = ebase[((95 - w) * 96 + h) * CC + c];
        float sv = (b == 0) ? nb : ((c == cm) ? nb : egov);
        sel[((size_t)bj * HW + p) * CC + c] = sv;
        if (j == 0) ego[((size_t)b * HW + p) * CC + c] = egov;
        if (c == 0) roi[(size_t)bj * HW + p] = f00 + f10 + f01 + f11;
    }
}

// ---------------- per-pixel MLP via bf16 MFMA: 256->128->32->8->1 ----------------
__global__ __launch_bounds__(256, 4) void k_mlp(
    const float* __restrict__ sel, const float* __restrict__ ego,
    const unsigned short* __restrict__ w1b, const unsigned short* __restrict__ w2b,
    const float* __restrict__ b1, const float* __restrict__ s1, const float* __restrict__ t1,
    const float* __restrict__ b2, const float* __restrict__ s2, const float* __restrict__ t2,
    const float* __restrict__ w3, const float* __restrict__ b3, const float* __restrict__ s3,
    const float* __restrict__ t3, const float* __restrict__ w4, const float* __restrict__ b4,
    float* __restrict__ logi) {
    __shared__ __align__(16) unsigned char sm[32768];
    int t = threadIdx.x;
    int blk = blockIdx.x;
    int bj = blk / 144, pt = blk - bj * 144;
    int b = bj >> 2;
    int p0 = pt * 64;
    const float* selp = sel + ((size_t)bj * HW + p0) * CC;
    const float* egop = ego + ((size_t)b * HW + p0) * CC;
    // ---- stage X = [sel || ego] as bf16 [64px][256k], XOR-swizzled (T2) ----
    #pragma unroll 4
    for (int it = 0; it < 32; it++) {
        int i = t + it * 256;
        int px = i >> 7, kp = i & 127;
        float2 v;
        if (kp < 64) v = *(const float2*)(selp + px * 128 + kp * 2);
        else         v = *(const float2*)(egop + px * 128 + (kp - 64) * 2);
        unsigned int pk = (unsigned int)f2bf(v.x) | ((unsigned int)f2bf(v.y) << 16);
        int kb = kp * 4;
        *(unsigned int*)(sm + px * 512 + (kb ^ ((px & 7) << 4))) = pk;
    }
    int lane = t & 63;
    int w = t >> 6;
    int l15 = lane & 15;
    int l4 = lane >> 4;
    float bb[2], ss[2], tt[2];
    #pragma unroll
    for (int nt = 0; nt < 2; nt++) {
        int o = w * 32 + nt * 16 + l15;
        bb[nt] = b1[o]; ss[nt] = s1[o]; tt[nt] = t1[o];
    }
    __syncthreads();
    // ---- GEMM1: C[64px][32out(this wave)] = X[64][256] @ W1^T ----
    f32x4 acc[4][2];
    #pragma unroll
    for (int mt = 0; mt < 4; mt++)
        #pragma unroll
        for (int nt = 0; nt < 2; nt++) acc[mt][nt] = f32x4{0.f, 0.f, 0.f, 0.f};
    const unsigned short* wb = w1b + (size_t)(w * 32) * 256;
    s16x8 bcur[2], bnxt[2];
    #pragma unroll
    for (int nt = 0; nt < 2; nt++)
        bcur[nt] = *(const s16x8*)(wb + (nt * 16 + l15) * 256 + l4 * 8);
    #pragma unroll
    for (int kt = 0; kt < 8; kt++) {
        if (kt < 7) {
            #pragma unroll
            for (int nt = 0; nt < 2; nt++)
                bnxt[nt] = *(const s16x8*)(wb + (nt * 16 + l15) * 256 + (kt + 1) * 32 + l4 * 8);
        }
        int k0 = kt * 32 + l4 * 8;
        #pragma unroll
        for (int mt = 0; mt < 4; mt++) {
            int px = mt * 16 + l15;
            s16x8 af = *(const s16x8*)(sm + px * 512 + ((2 * k0) ^ ((px & 7) << 4)));
            #pragma unroll
            for (int nt = 0; nt < 2; nt++)
                acc[mt][nt] = __builtin_amdgcn_mfma_f32_16x16x32_bf16(af, bcur[nt], acc[mt][nt], 0, 0, 0);
        }
        #pragma unroll
        for (int nt = 0; nt < 2; nt++) bcur[nt] = bnxt[nt];
    }
    __syncthreads();
    // ---- epilogue1: affine+relu -> L1s bf16 [64px][128] swizzled (overlays Xs) ----
    #pragma unroll
    for (int mt = 0; mt < 4; mt++) {
        #pragma unroll
        for (int nt = 0; nt < 2; nt++) {
            int o = w * 32 + nt * 16 + l15;
            #pragma unroll
            for (int r = 0; r < 4; r++) {
                int px = mt * 16 + l4 * 4 + r;
                float v = (acc[mt][nt][r] + bb[nt]) * ss[nt] + tt[nt];
                v = fmaxf(v, 0.f);
                *(unsigned short*)(sm + px * 256 + ((2 * o) ^ ((px & 7) << 4))) = f2bf(v);
            }
        }
    }
    __syncthreads();
    // ---- GEMM2: C[16px(this wave)][32out] = L1[16][128] @ W2^T ----
    f32x4 acc2[2];
    acc2[0] = f32x4{0.f, 0.f, 0.f, 0.f};
    acc2[1] = f32x4{0.f, 0.f, 0.f, 0.f};
    s16x8 b2f[2][4];
    #pragma unroll
    for (int nt = 0; nt < 2; nt++)
        #pragma unroll
        for (int kt = 0; kt < 4; kt++)
            b2f[nt][kt] = *(const s16x8*)(w2b + (nt * 16 + l15) * 128 + kt * 32 + l4 * 8);
    #pragma unroll
    for (int kt = 0; kt < 4; kt++) {
        int px = w * 16 + l15;
        int k0 = kt * 32 + l4 * 8;
        s16x8 af = *(const s16x8*)(sm + px * 256 + ((2 * k0) ^ ((px & 7) << 4)));
        #pragma unroll
        for (int nt = 0; nt < 2; nt++)
            acc2[nt] = __builtin_amdgcn_mfma_f32_16x16x32_bf16(af, b2f[nt][kt], acc2[nt], 0, 0, 0);
    }
    float* l2s = (float*)(sm + 16384);
    #pragma unroll
    for (int nt = 0; nt < 2; nt++) {
        int o = nt * 16 + l15;
        float b2v = b2[o], s2v = s2[o], t2v = t2[o];
        #pragma unroll
        for (int r = 0; r < 4; r++) {
            int px = w * 16 + l4 * 4 + r;
            float v = (acc2[nt][r] + b2v) * s2v + t2v;
            l2s[px * 37 + o] = fmaxf(v, 0.f);
        }
    }
    __syncthreads();
    // ---- layers 3+4 (fp32 VALU, wave 0) ----
    if (t < 64) {
        int px = t;
        float xv[32];
        #pragma unroll
        for (int k = 0; k < 32; k++) xv[k] = l2s[px * 37 + k];
        float lg = b4[0];
        #pragma unroll
        for (int o = 0; o < 8; o++) {
            float a = 0.f;
            #pragma unroll
            for (int k = 0; k < 32; k++) a += xv[k] * w3[o * 32 + k];
            float l3v = fmaxf((a + b3[o]) * s3[o] + t3[o], 0.f);
            lg += w4[o] * l3v;
        }
        logi[(size_t)bj * HW + p0 + px] = fmaxf(lg, 0.f);
    }
}

// ---------------- fused softmax-combine + final 128x128 MLP + un-flip writeback ----------------
// block = 256 thr (4 waves), 32 px. LDS: fused bf16 [32px][128] swizzled (8KB) + wgt (512B).
__global__ __launch_bounds__(256, 4) void k_fuseout(
    const float* __restrict__ sel, const float* __restrict__ roi, const float* __restrict__ logi,
    const unsigned short* __restrict__ mwb, const float* __restrict__ mb, float* __restrict__ out) {
    __shared__ __align__(16) unsigned char sm[8704];
    float* wgt = (float*)(sm + 8192);   // [4][32]
    int t = threadIdx.x;
    int blk = blockIdx.x;
    int b = blk / 288, pt = blk - b * 288;
    int p0 = pt * 32;
    // ---- softmax weights (threads 0..31, one px each) ----
    if (t < 32) {
        int p = p0 + t;
        float lg[4], rr[4];
        #pragma unroll
        for (int j = 0; j < 4; j++) {
            rr[j] = roi[(size_t)(b * 4 + j) * HW + p];
            lg[j] = logi[(size_t)(b * 4 + j) * HW + p];
        }
        float m = -1e30f;
        #pragma unroll
        for (int j = 0; j < 4; j++) if (rr[j] != 0.f && lg[j] > m) m = lg[j];
        float e[4], se = 0.f;
        #pragma unroll
        for (int j = 0; j < 4; j++) { e[j] = (rr[j] != 0.f) ? expf(lg[j] - m) : 0.f; se += e[j]; }
        float inv = 1.f / se;
        #pragma unroll
        for (int j = 0; j < 4; j++) wgt[j * 32 + t] = e[j] * inv * rr[j];
    }
    __syncthreads();
    // ---- weighted combine -> bf16 LDS (swizzled). 8 float2 per thread ----
    float2 a8[8];
    #pragma unroll
    for (int it = 0; it < 8; it++) a8[it] = float2{0.f, 0.f};
    #pragma unroll
    for (int j = 0; j < 4; j++) {
        const float* sp = sel + ((size_t)(b * 4 + j) * HW + p0) * CC;
        #pragma unroll
        for (int it = 0; it < 8; it++) {
            int i = it * 256 + t;
            int px = i >> 6, cp = i & 63;
            float wv = wgt[j * 32 + px];
            float2 v = *(const float2*)(sp + px * 128 + cp * 2);
            a8[it].x += wv * v.x; a8[it].y += wv * v.y;
        }
    }
    #pragma unroll
    for (int it = 0; it < 8; it++) {
        int i = it * 256 + t;
        int px = i >> 6, cp = i & 63;
        unsigned int pk = (unsigned int)f2bf(a8[it].x) | ((unsigned int)f2bf(a8[it].y) << 16);
        *(unsigned int*)(sm + px * 256 + ((cp * 4) ^ ((px & 7) << 4))) = pk;
    }
    __syncthreads();
    // ---- GEMM: out[32px][128] = fused[32][128] @ mw^T ----
    int lane = t & 63, w = t >> 6, l15 = lane & 15, l4 = lane >> 4;
    f32x4 acc[2][2];
    #pragma unroll
    for (int mt = 0; mt < 2; mt++)
        #pragma unroll
        for (int nt = 0; nt < 2; nt++) acc[mt][nt] = f32x4{0.f, 0.f, 0.f, 0.f};
    s16x8 bf[2][4];
    #pragma unroll
    for (int nt = 0; nt < 2; nt++)
        #pragma unroll
        for (int kt = 0; kt < 4; kt++)
            bf[nt][kt] = *(const s16x8*)(mwb + (w * 32 + nt * 16 + l15) * 128 + kt * 32 + l4 * 8);
    #pragma unroll
    for (int kt = 0; kt < 4; kt++) {
        #pragma unroll
        for (int mt = 0; mt < 2; mt++) {
            int px = mt * 16 + l15;
            s16x8 af = *(const s16x8*)(sm + px * 256 + ((kt * 64 + l4 * 16) ^ ((px & 7) << 4)));
            #pragma unroll
            for (int nt = 0; nt < 2; nt++)
                acc[mt][nt] = __builtin_amdgcn_mfma_f32_16x16x32_bf16(af, bf[nt][kt], acc[mt][nt], 0, 0, 0);
        }
    }
    float mbv[2];
    #pragma unroll
    for (int nt = 0; nt < 2; nt++) mbv[nt] = mb[w * 32 + nt * 16 + l15];
    #pragma unroll
    for (int mt = 0; mt < 2; mt++) {
        #pragma unroll
        for (int nt = 0; nt < 2; nt++) {
            #pragma unroll
            for (int r = 0; r < 4; r++) {
                int px = mt * 16 + l4 * 4 + r;
                int p = p0 + px;
                int h = p / 96, ww = p - h * 96;
                out[(((size_t)b * 96 + (95 - ww)) * 96 + h) * CC + w * 32 + nt * 16 + l15] = acc[mt][nt][r] + mbv[nt];
            }
        }
    }
}

extern "C" void kernel_launch(void* const* d_in, const int* in_sizes, int n_in,
                              void* d_out, int out_size, void* d_ws, size_t ws_size,
                              hipStream_t stream) {
    const float* x  = (const float*)d_in[0];
    const float* P  = (const float*)d_in[2];
    const float* w1 = (const float*)d_in[3];
    const float* b1 = (const float*)d_in[4];
    const float* s1 = (const float*)d_in[5];
    const float* t1 = (const float*)d_in[6];
    const float* w2 = (const float*)d_in[7];
    const float* b2 = (const float*)d_in[8];
    const float* s2 = (const float*)d_in[9];
    const float* t2 = (const float*)d_in[10];
    const float* w3 = (const float*)d_in[11];
    const float* b3 = (const float*)d_in[12];
    const float* s3 = (const float*)d_in[13];
    const float* t3 = (const float*)d_in[14];
    const float* w4 = (const float*)d_in[15];
    const float* b4 = (const float*)d_in[16];
    const float* mw = (const float*)d_in[17];
    const float* mb = (const float*)d_in[18];
    float* out = (float*)d_out;

    float* ws   = (float*)d_ws;
    float* TH   = ws;                    // 48
    float* VAR  = ws + 64;               // 256
    int*   CMX  = (int*)(ws + 320);      // 2
    float* XT   = ws + 384;              // 2*4*96*96*128 = 9437184
    float* SEL  = XT + 9437184;          // 9437184
    float* EGO  = SEL + 9437184;         // 2359296
    float* ROI  = EGO + 2359296;         // 73728
    float* LOGI = ROI + 73728;           // 73728
    unsigned short* W1B = (unsigned short*)(LOGI + 73728);  // 32768 bf16
    unsigned short* W2B = W1B + 32768;                      // 4096 bf16
    unsigned short* MWB = W2B + 4096;                       // 16384 bf16

    k_theta<<<1, 64, 0, stream>>>(P, TH);
    k_wcvt<<<32, 256, 0, stream>>>(w1, w2, mw, W1B, W2B, MWB);
    k_transpose<<<768, 256, 0, stream>>>(x, XT);
    k_var<<<256, 256, 0, stream>>>(x, VAR);
    k_argmax<<<2, 128, 0, stream>>>(VAR, CMX);
    k_gather<<<4608, 256, 0, stream>>>(XT, TH, CMX, SEL, EGO, ROI);
    k_mlp<<<1152, 256, 0, stream>>>(SEL, EGO, W1B, W2B, b1, s1, t1, b2, s2, t2,
                                    w3, b3, s3, t3, w4, b4, LOGI);
    k_fuseout<<<576, 256, 0, stream>>>(SEL, ROI, LOGI, MWB, mb, out);
}

// Round 4
// 185.917 us; speedup vs baseline: 2.6347x; 1.0725x over previous
//
#include <hip/hip_runtime.h>
#include <hip/hip_bf16.h>
#include <math.h>

// B=2, L=4, C=128, H=W=96. Only fusion target i=0 is consumed downstream.
// j=0 source is the identity warp: sel[b][0]==ego, roi[b][0]==1 (diag of P is I).
#define HW 9216
#define CC 128

typedef __attribute__((ext_vector_type(4))) float f32x4;
typedef __attribute__((ext_vector_type(8))) short s16x8;

static __device__ __forceinline__ unsigned short f2bf(float f) {
    __hip_bfloat16 h = __float2bfloat16(f);
    return *reinterpret_cast<unsigned short*>(&h);
}
static __device__ __forceinline__ float bf2f(unsigned short u) {
    unsigned int v = ((unsigned int)u) << 16;
    float f;
    __builtin_memcpy(&f, &v, 4);
    return f;
}

// ---------------- theta setup: 8 (b,j) affine matrices ----------------
__global__ void k_theta(const float* __restrict__ P, float* __restrict__ th) {
    int t = threadIdx.x;
    if (t >= 8) return;
    int b = t >> 2, j = t & 3;
    const float* M = P + (size_t)(b * 4 + j) * 64;
    float a00 = M[0], a01 = M[1], a02 = M[3] / 1.6f;
    float a10 = M[4], a11 = M[5], a12 = M[7] / 1.6f;
    const float cx = 48.f, cy = 48.f;
    float T02 = cx - (a00 * cx + a01 * cy) + a02;
    float T12 = cy - (a10 * cx + a11 * cy) + a12;
    float A02 = a00 + a01 - 1.f + (2.f / 95.f) * T02;
    float A12 = a10 + a11 - 1.f + (2.f / 95.f) * T12;
    float det = a00 * a11 - a01 * a10;
    float i00 = a11 / det, i01 = -a01 / det, i10 = -a10 / det, i11 = a00 / det;
    float* o = th + t * 6;
    o[0] = i00; o[1] = i01; o[2] = -(i00 * A02 + i01 * A12);
    o[3] = i10; o[4] = i11; o[5] = -(i10 * A02 + i11 * A12);
}

// ---------------- convert w1,w2,mlp_w to bf16 tables ----------------
__global__ __launch_bounds__(256) void k_wcvt(const float* __restrict__ w1, const float* __restrict__ w2,
                                              const float* __restrict__ mw,
                                              unsigned short* __restrict__ w1b, unsigned short* __restrict__ w2b,
                                              unsigned short* __restrict__ mwb) {
    int t = blockIdx.x * 256 + threadIdx.x;
    int nthr = gridDim.x * 256;
    for (int i = t; i < 32768; i += nthr) w1b[i] = f2bf(w1[i]);
    for (int i = t; i < 16384; i += nthr) mwb[i] = f2bf(mw[i]);
    if (t < 4096) w2b[t] = f2bf(w2[t]);
}

// ---------------- transpose x -> channel-last bf16 xT[bn][y][x][c] ----------------
__global__ __launch_bounds__(256) void k_transpose(const float* __restrict__ x, unsigned short* __restrict__ xT) {
    int bn = blockIdx.x / 96, y = blockIdx.x % 96;
    __shared__ float tile[96][129];
    const float* src = x + (size_t)bn * 128 * HW + (size_t)y * 96;
    for (int i = threadIdx.x; i < 128 * 96; i += 256) {
        int c = i / 96, xx = i - c * 96;
        tile[xx][c] = src[(size_t)c * HW + xx];
    }
    __syncthreads();
    unsigned int* dst = (unsigned int*)(xT + ((size_t)bn * 96 + y) * 96 * 128);
    for (int i = threadIdx.x; i < 96 * 64; i += 256) {
        int xx = i >> 6, cp = i & 63;
        unsigned int pk = (unsigned int)f2bf(tile[xx][cp * 2]) | ((unsigned int)f2bf(tile[xx][cp * 2 + 1]) << 16);
        dst[xx * 64 + cp] = pk;
    }
}

// ---------------- per-channel variance of agent-0 feats (ddof=1) ----------------
__global__ __launch_bounds__(256) void k_var(const float* __restrict__ x, float* __restrict__ var) {
    int b = blockIdx.x >> 7, c = blockIdx.x & 127;
    const float* src = x + ((size_t)(b * 4) * 128 + c) * HW;
    float s = 0.f, ss = 0.f;
    for (int i = threadIdx.x; i < HW; i += 256) { float v = src[i]; s += v; ss += v * v; }
    __shared__ float rs[256], rss[256];
    rs[threadIdx.x] = s; rss[threadIdx.x] = ss; __syncthreads();
    for (int o = 128; o > 0; o >>= 1) {
        if (threadIdx.x < o) { rs[threadIdx.x] += rs[threadIdx.x + o]; rss[threadIdx.x] += rss[threadIdx.x + o]; }
        __syncthreads();
    }
    if (threadIdx.x == 0) {
        float mean = rs[0] / 9216.f;
        var[b * 128 + c] = (rss[0] - 9216.f * mean * mean) / 9215.f;
    }
}

__global__ void k_argmax(const float* __restrict__ var, int* __restrict__ cmax) {
    int b = blockIdx.x, t = threadIdx.x;
    __shared__ float v[128]; __shared__ int idx[128];
    v[t] = var[b * 128 + t]; idx[t] = t; __syncthreads();
    for (int o = 64; o > 0; o >>= 1) {
        if (t < o) { if (v[t + o] > v[t]) { v[t] = v[t + o]; idx[t] = idx[t + o]; } }
        __syncthreads();
    }
    if (t == 0) cmax[b] = idx[0];
}

// ---------------- gather (j=1..3 only): sel16[b3][p][c] bf16, roi[b3][p] ----------------
__global__ __launch_bounds__(256) void k_gather(const unsigned short* __restrict__ xT, const float* __restrict__ th,
                                                const int* __restrict__ cmax, unsigned short* __restrict__ sel16,
                                                float* __restrict__ roi) {
    int blk = blockIdx.x;
    int bj6 = blk / 576, pblk = blk - bj6 * 576;
    int b = bj6 / 3, jm = bj6 - b * 3, j = jm + 1;
    int pr = threadIdx.x >> 7, c = threadIdx.x & 127;
    const float* t6 = th + (b * 4 + j) * 6;
    float T0 = t6[0], T1 = t6[1], T2 = t6[2], T3 = t6[3], T4 = t6[4], T5 = t6[5];
    int cm = cmax[b];
    const unsigned short* base = xT + (size_t)(b * 4 + j) * HW * CC;
    const unsigned short* ebase = xT + (size_t)(b * 4) * HW * CC;
    #pragma unroll
    for (int it = 0; it < 8; it++) {
        int p = pblk * 16 + it * 2 + pr;
        int h = p / 96, w = p - h * 96;
        float X = -1.f + (2.f / 95.f) * (float)w, Y = -1.f + (2.f / 95.f) * (float)h;
        float gx = T0 * X + T1 * Y + T2;
        float gy = T3 * X + T4 * Y + T5;
        float px = (gx + 1.f) * 47.5f, py = (gy + 1.f) * 47.5f;
        float x0f = floorf(px), y0f = floorf(py);
        float wx = px - x0f, wy = py - y0f;
        int x0 = (int)x0f, y0 = (int)y0f, x1 = x0 + 1, y1 = y0 + 1;
        float w00 = (1.f - wx) * (1.f - wy), w10 = wx * (1.f - wy);
        float w01 = (1.f - wx) * wy, w11 = wx * wy;
        bool vx0 = (x0 >= 0) && (x0 <= 95), vx1 = (x1 >= 0) && (x1 <= 95);
        bool vy0 = (y0 >= 0) && (y0 <= 95), vy1 = (y1 >= 0) && (y1 <= 95);
        float f00 = (vx0 && vy0) ? w00 : 0.f, f10 = (vx1 && vy0) ? w10 : 0.f;
        float f01 = (vx0 && vy1) ? w01 : 0.f, f11 = (vx1 && vy1) ? w11 : 0.f;
        int xc0 = min(max(x0, 0), 95), xc1 = min(max(x1, 0), 95);
        int yc0 = min(max(y0, 0), 95), yc1 = min(max(y1, 0), 95);
        float nb = f00 * bf2f(base[((95 - xc0) * 96 + yc0) * CC + c])
                 + f10 * bf2f(base[((95 - xc1) * 96 + yc0) * CC + c])
                 + f01 * bf2f(base[((95 - xc0) * 96 + yc1) * CC + c])
                 + f11 * bf2f(base[((95 - xc1) * 96 + yc1) * CC + c]);
        unsigned short egov = ebase[((95 - w) * 96 + h) * CC + c];
        unsigned short sv = (b == 0) ? f2bf(nb) : ((c == cm) ? f2bf(nb) : egov);
        sel16[((size_t)bj6 * HW + p) * CC + c] = sv;
        if (c == 0) roi[(size_t)bj6 * HW + p] = f00 + f10 + f01 + f11;
    }
}

// ---------------- mega-fused: 4-source MLP -> softmax -> combine -> final GEMM ----------------
// block = 256 thr (4 waves), 32 px. LDS 47232 B -> 3 blocks/CU.
__global__ __launch_bounds__(256) void k_fused(
    const unsigned short* __restrict__ xT, const unsigned short* __restrict__ sel16,
    const float* __restrict__ roiB,
    const unsigned short* __restrict__ w1b, const unsigned short* __restrict__ w2b,
    const unsigned short* __restrict__ mwb,
    const float* __restrict__ b1, const float* __restrict__ s1, const float* __restrict__ t1,
    const float* __restrict__ b2, const float* __restrict__ s2, const float* __restrict__ t2,
    const float* __restrict__ w3, const float* __restrict__ b3, const float* __restrict__ s3,
    const float* __restrict__ t3, const float* __restrict__ w4, const float* __restrict__ b4,
    const float* __restrict__ mb, float* __restrict__ out) {
    __shared__ __align__(16) unsigned char sm[47232];
    // layout: selT[j] @ j*8192 (j=0 is ego), l1T @32768(8KB), l2s @40960(4736B),
    //         lgs @45696, rois @46208, wgt @46720 (512B each)
    float* l2s  = (float*)(sm + 40960);
    float* lgs  = (float*)(sm + 45696);
    float* rois = (float*)(sm + 46208);
    float* wgt  = (float*)(sm + 46720);
    int t = threadIdx.x;
    int blk = blockIdx.x;
    int b = blk / 288, pt = blk - b * 288;
    int p0 = pt * 32;
    // ---- stage ego (slot 0) from xT, sel j=1..3 from sel16; all swizzled ----
    const unsigned short* egb = xT + (size_t)(b * 4) * HW * CC;
    #pragma unroll
    for (int it = 0; it < 2; it++) {
        int u = it * 256 + t;
        int px = u >> 4, g = u & 15;
        int p = p0 + px;
        int h = p / 96, w = p - h * 96;
        s16x8 v = *(const s16x8*)(egb + (size_t)((95 - w) * 96 + h) * CC + g * 8);
        *(s16x8*)(sm + px * 256 + ((g * 16) ^ ((px & 7) << 4))) = v;
    }
    #pragma unroll
    for (int j = 1; j < 4; j++) {
        const unsigned short* sp = sel16 + ((size_t)(b * 3 + j - 1) * HW + p0) * CC;
        #pragma unroll
        for (int it = 0; it < 2; it++) {
            int u = it * 256 + t;
            int px = u >> 4, g = u & 15;
            s16x8 v = *(const s16x8*)(sp + px * 128 + g * 8);
            *(s16x8*)(sm + j * 8192 + px * 256 + ((g * 16) ^ ((px & 7) << 4))) = v;
        }
    }
    if (t < 128) {
        int j = t >> 5, px = t & 31;
        rois[j * 32 + px] = (j == 0) ? 1.f : roiB[(size_t)(b * 3 + j - 1) * HW + p0 + px];
    }
    int lane = t & 63, w_ = t >> 6, l15 = lane & 15, l4 = lane >> 4;
    float bb[2], ss[2], tt[2];
    #pragma unroll
    for (int nt = 0; nt < 2; nt++) {
        int o = w_ * 32 + nt * 16 + l15;
        bb[nt] = b1[o]; ss[nt] = s1[o]; tt[nt] = t1[o];
    }
    int mt2 = w_ >> 1, nt2 = w_ & 1;
    float b2v, s2v, t2v;
    { int o2 = nt2 * 16 + l15; b2v = b2[o2]; s2v = s2[o2]; t2v = t2[o2]; }
    __syncthreads();
    // ---- per-source MLP loop ----
    for (int j = 0; j < 4; j++) {
        // GEMM1: C[32px][32out(this wave)] = [sel_j || ego][32][256] @ W1^T
        f32x4 acc[2][2];
        #pragma unroll
        for (int mt = 0; mt < 2; mt++)
            #pragma unroll
            for (int nt = 0; nt < 2; nt++) acc[mt][nt] = f32x4{0.f, 0.f, 0.f, 0.f};
        const unsigned char* selj = sm + j * 8192;
        #pragma unroll
        for (int kt = 0; kt < 8; kt++) {
            const unsigned char* src = (kt < 4) ? selj : sm;  // cols 128..255 = ego
            int kloc = (kt & 3) * 32 + l4 * 8;
            s16x8 bfr[2];
            #pragma unroll
            for (int nt = 0; nt < 2; nt++)
                bfr[nt] = *(const s16x8*)(w1b + (size_t)(w_ * 32 + nt * 16 + l15) * 256 + kt * 32 + l4 * 8);
            #pragma unroll
            for (int mt = 0; mt < 2; mt++) {
                int px = mt * 16 + l15;
                s16x8 af = *(const s16x8*)(src + px * 256 + ((2 * kloc) ^ ((px & 7) << 4)));
                #pragma unroll
                for (int nt = 0; nt < 2; nt++)
                    acc[mt][nt] = __builtin_amdgcn_mfma_f32_16x16x32_bf16(af, bfr[nt], acc[mt][nt], 0, 0, 0);
            }
        }
        __syncthreads();  // l1T/l2s safe to overwrite (prev iter readers done)
        // epilogue1: affine+relu -> l1T bf16 swizzled [32][128]
        #pragma unroll
        for (int mt = 0; mt < 2; mt++) {
            #pragma unroll
            for (int nt = 0; nt < 2; nt++) {
                int o = w_ * 32 + nt * 16 + l15;
                #pragma unroll
                for (int r = 0; r < 4; r++) {
                    int px = mt * 16 + l4 * 4 + r;
                    float v = fmaxf((acc[mt][nt][r] + bb[nt]) * ss[nt] + tt[nt], 0.f);
                    *(unsigned short*)(sm + 32768 + px * 256 + ((2 * o) ^ ((px & 7) << 4))) = f2bf(v);
                }
            }
        }
        __syncthreads();
        // GEMM2: C[32][32]; wave tile (mt2,nt2)
        f32x4 acc2 = f32x4{0.f, 0.f, 0.f, 0.f};
        {
            int px = mt2 * 16 + l15;
            #pragma unroll
            for (int kt = 0; kt < 4; kt++) {
                s16x8 af = *(const s16x8*)(sm + 32768 + px * 256 + ((2 * (kt * 32 + l4 * 8)) ^ ((px & 7) << 4)));
                s16x8 bf = *(const s16x8*)(w2b + (size_t)(nt2 * 16 + l15) * 128 + kt * 32 + l4 * 8);
                acc2 = __builtin_amdgcn_mfma_f32_16x16x32_bf16(af, bf, acc2, 0, 0, 0);
            }
        }
        // epilogue2 -> l2s f32 [32][37]
        {
            int o2 = nt2 * 16 + l15;
            #pragma unroll
            for (int r = 0; r < 4; r++) {
                int pxr = mt2 * 16 + l4 * 4 + r;
                l2s[pxr * 37 + o2] = fmaxf((acc2[r] + b2v) * s2v + t2v, 0.f);
            }
        }
        __syncthreads();
        // layers 3+4 (threads 0..31, one px each)
        if (t < 32) {
            int px = t;
            float xv[32];
            #pragma unroll
            for (int k = 0; k < 32; k++) xv[k] = l2s[px * 37 + k];
            float lg = b4[0];
            #pragma unroll
            for (int o = 0; o < 8; o++) {
                float a = 0.f;
                #pragma unroll
                for (int k = 0; k < 32; k++) a += xv[k] * w3[o * 32 + k];
                float l3v = fmaxf((a + b3[o]) * s3[o] + t3[o], 0.f);
                lg += w4[o] * l3v;
            }
            lgs[j * 32 + px] = fmaxf(lg, 0.f);
        }
    }
    __syncthreads();
    // ---- softmax weights ----
    if (t < 32) {
        int px = t;
        float rr[4], lg[4];
        #pragma unroll
        for (int j = 0; j < 4; j++) { rr[j] = rois[j * 32 + px]; lg[j] = lgs[j * 32 + px]; }
        float m = -1e30f;
        #pragma unroll
        for (int j = 0; j < 4; j++) if (rr[j] != 0.f && lg[j] > m) m = lg[j];
        float e[4], se = 0.f;
        #pragma unroll
        for (int j = 0; j < 4; j++) { e[j] = (rr[j] != 0.f) ? expf(lg[j] - m) : 0.f; se += e[j]; }
        float inv = 1.f / se;
        #pragma unroll
        for (int j = 0; j < 4; j++) wgt[j * 32 + px] = e[j] * inv * rr[j];
    }
    __syncthreads();
    // ---- weighted combine from LDS sel tiles -> fused bf16 (reuse l1T) ----
    #pragma unroll
    for (int it = 0; it < 2; it++) {
        int u = it * 256 + t;
        int px = u >> 4, g = u & 15;
        int byo = (g * 16) ^ ((px & 7) << 4);
        float wj[4];
        #pragma unroll
        for (int j = 0; j < 4; j++) wj[j] = wgt[j * 32 + px];
        float accv[8];
        #pragma unroll
        for (int e = 0; e < 8; e++) accv[e] = 0.f;
        #pragma unroll
        for (int j = 0; j < 4; j++) {
            s16x8 v = *(const s16x8*)(sm + j * 8192 + px * 256 + byo);
            #pragma unroll
            for (int e = 0; e < 8; e++) accv[e] += wj[j] * bf2f((unsigned short)v[e]);
        }
        s16x8 pk;
        #pragma unroll
        for (int e = 0; e < 8; e++) pk[e] = (short)f2bf(accv[e]);
        *(s16x8*)(sm + 32768 + px * 256 + byo) = pk;
    }
    __syncthreads();
    // ---- final GEMM: out[32px][128] = fused @ mw^T + mb, un-flip writeback ----
    f32x4 acc3[2][2];
    #pragma unroll
    for (int mt = 0; mt < 2; mt++)
        #pragma unroll
        for (int nt = 0; nt < 2; nt++) acc3[mt][nt] = f32x4{0.f, 0.f, 0.f, 0.f};
    #pragma unroll
    for (int kt = 0; kt < 4; kt++) {
        s16x8 bfr[2];
        #pragma unroll
        for (int nt = 0; nt < 2; nt++)
            bfr[nt] = *(const s16x8*)(mwb + (size_t)(w_ * 32 + nt * 16 + l15) * 128 + kt * 32 + l4 * 8);
        #pragma unroll
        for (int mt = 0; mt < 2; mt++) {
            int px = mt * 16 + l15;
            s16x8 af = *(const s16x8*)(sm + 32768 + px * 256 + ((kt * 64 + l4 * 16) ^ ((px & 7) << 4)));
            #pragma unroll
            for (int nt = 0; nt < 2; nt++)
                acc3[mt][nt] = __builtin_amdgcn_mfma_f32_16x16x32_bf16(af, bfr[nt], acc3[mt][nt], 0, 0, 0);
        }
    }
    float mbv[2];
    #pragma unroll
    for (int nt = 0; nt < 2; nt++) mbv[nt] = mb[w_ * 32 + nt * 16 + l15];
    #pragma unroll
    for (int mt = 0; mt < 2; mt++) {
        #pragma unroll
        for (int nt = 0; nt < 2; nt++) {
            #pragma unroll
            for (int r = 0; r < 4; r++) {
                int px = mt * 16 + l4 * 4 + r;
                int p = p0 + px;
                int h = p / 96, ww = p - h * 96;
                out[(((size_t)b * 96 + (95 - ww)) * 96 + h) * CC + w_ * 32 + nt * 16 + l15] = acc3[mt][nt][r] + mbv[nt];
            }
        }
    }
}

extern "C" void kernel_launch(void* const* d_in, const int* in_sizes, int n_in,
                              void* d_out, int out_size, void* d_ws, size_t ws_size,
                              hipStream_t stream) {
    const float* x  = (const float*)d_in[0];
    const float* P  = (const float*)d_in[2];
    const float* w1 = (const float*)d_in[3];
    const float* b1 = (const float*)d_in[4];
    const float* s1 = (const float*)d_in[5];
    const float* t1 = (const float*)d_in[6];
    const float* w2 = (const float*)d_in[7];
    const float* b2 = (const float*)d_in[8];
    const float* s2 = (const float*)d_in[9];
    const float* t2 = (const float*)d_in[10];
    const float* w3 = (const float*)d_in[11];
    const float* b3 = (const float*)d_in[12];
    const float* s3 = (const float*)d_in[13];
    const float* t3 = (const float*)d_in[14];
    const float* w4 = (const float*)d_in[15];
    const float* b4 = (const float*)d_in[16];
    const float* mw = (const float*)d_in[17];
    const float* mb = (const float*)d_in[18];
    float* out = (float*)d_out;

    float* ws = (float*)d_ws;
    float* TH  = ws;                                     // 48 (pad 64)
    float* VAR = ws + 64;                                // 256
    int*   CMX = (int*)(ws + 320);                       // 2 (pad to 384)
    unsigned short* XT    = (unsigned short*)(ws + 384); // 8*HW*128 = 9437184 bf16
    unsigned short* SEL16 = XT + 9437184;                // 6*HW*128 = 7077888 bf16
    float* ROI = (float*)(SEL16 + 7077888);              // 6*HW = 55296
    unsigned short* W1B = (unsigned short*)(ROI + 55296);// 32768
    unsigned short* W2B = W1B + 32768;                   // 4096
    unsigned short* MWB = W2B + 4096;                    // 16384

    k_theta<<<1, 64, 0, stream>>>(P, TH);
    k_wcvt<<<32, 256, 0, stream>>>(w1, w2, mw, W1B, W2B, MWB);
    k_transpose<<<768, 256, 0, stream>>>(x, XT);
    k_var<<<256, 256, 0, stream>>>(x, VAR);
    k_argmax<<<2, 128, 0, stream>>>(VAR, CMX);
    k_gather<<<3456, 256, 0, stream>>>(XT, TH, CMX, SEL16, ROI);
    k_fused<<<576, 256, 0, stream>>>(XT, SEL16, ROI, W1B, W2B, MWB,
                                     b1, s1, t1, b2, s2, t2, w3, b3, s3, t3, w4, b4, mb, out);
}

// Round 6
// 184.309 us; speedup vs baseline: 2.6576x; 1.0087x over previous
//
#include <hip/hip_runtime.h>
#include <hip/hip_bf16.h>
#include <math.h>

// B=2, L=4, C=128, H=W=96. Only fusion target i=0 is consumed downstream.
// j=0 source is the identity warp: sel[b][0]==ego, roi[b][0]==1 (diag of P is I).
#define HW 9216
#define CC 128

typedef __attribute__((ext_vector_type(4))) float f32x4;
typedef __attribute__((ext_vector_type(8))) short s16x8;

static __device__ __forceinline__ unsigned short f2bf(float f) {
    __hip_bfloat16 h = __float2bfloat16(f);
    return *reinterpret_cast<unsigned short*>(&h);
}
static __device__ __forceinline__ float bf2f(unsigned short u) {
    unsigned int v = ((unsigned int)u) << 16;
    float f;
    __builtin_memcpy(&f, &v, 4);
    return f;
}

// ---------------- prep: theta (block 0) + bf16 weight tables ----------------
__global__ __launch_bounds__(256) void k_prep(const float* __restrict__ P,
                                              const float* __restrict__ w1, const float* __restrict__ w2,
                                              const float* __restrict__ mw,
                                              float* __restrict__ th,
                                              unsigned short* __restrict__ w1b, unsigned short* __restrict__ w2b,
                                              unsigned short* __restrict__ mwb) {
    int t = blockIdx.x * 256 + threadIdx.x;
    if (blockIdx.x == 0 && threadIdx.x < 8) {
        int i = threadIdx.x;
        const float* M = P + (size_t)i * 64;
        float a00 = M[0], a01 = M[1], a02 = M[3] / 1.6f;
        float a10 = M[4], a11 = M[5], a12 = M[7] / 1.6f;
        const float cx = 48.f, cy = 48.f;
        float T02 = cx - (a00 * cx + a01 * cy) + a02;
        float T12 = cy - (a10 * cx + a11 * cy) + a12;
        float A02 = a00 + a01 - 1.f + (2.f / 95.f) * T02;
        float A12 = a10 + a11 - 1.f + (2.f / 95.f) * T12;
        float det = a00 * a11 - a01 * a10;
        float i00 = a11 / det, i01 = -a01 / det, i10 = -a10 / det, i11 = a00 / det;
        float* o = th + i * 6;
        o[0] = i00; o[1] = i01; o[2] = -(i00 * A02 + i01 * A12);
        o[3] = i10; o[4] = i11; o[5] = -(i10 * A02 + i11 * A12);
    }
    int nthr = gridDim.x * 256;
    for (int i = t; i < 32768; i += nthr) w1b[i] = f2bf(w1[i]);
    for (int i = t; i < 16384; i += nthr) mwb[i] = f2bf(mw[i]);
    for (int i = t; i < 4096; i += nthr) w2b[i] = f2bf(w2[i]);
}

// ---------------- transpose x -> bf16 xT[bn][y][x][c]; fused agent-0 var sums ----------------
__global__ __launch_bounds__(256) void k_transpose(const float* __restrict__ x, unsigned short* __restrict__ xT,
                                                   float* __restrict__ vsum) {
    int bn = blockIdx.x / 96, y = blockIdx.x % 96;
    __shared__ float tile[96][129];
    const float* src = x + (size_t)bn * 128 * HW + (size_t)y * 96;
    for (int i = threadIdx.x; i < 128 * 96; i += 256) {
        int c = i / 96, xx = i - c * 96;
        tile[xx][c] = src[(size_t)c * HW + xx];
    }
    __syncthreads();
    unsigned int* dst = (unsigned int*)(xT + ((size_t)bn * 96 + y) * 96 * 128);
    for (int i = threadIdx.x; i < 96 * 64; i += 256) {
        int xx = i >> 6, cp = i & 63;
        unsigned int pk = (unsigned int)f2bf(tile[xx][cp * 2]) | ((unsigned int)f2bf(tile[xx][cp * 2 + 1]) << 16);
        dst[xx * 64 + cp] = pk;
    }
    if ((bn & 3) == 0 && threadIdx.x < 128) {
        int c = threadIdx.x;
        float s = 0.f, ss = 0.f;
        #pragma unroll 8
        for (int xx = 0; xx < 96; xx++) { float v = tile[xx][c]; s += v; ss += v * v; }
        float* vp = vsum + (size_t)((bn >> 2) * 128 + c) * 2;
        atomicAdd(vp, s);
        atomicAdd(vp + 1, ss);
    }
}

// ---------------- argmax of per-channel variance (ddof=1) ----------------
__global__ void k_argmax(const float* __restrict__ vsum, int* __restrict__ cmax) {
    int b = blockIdx.x, t = threadIdx.x;  // 128 threads
    __shared__ float v[128]; __shared__ int idx[128];
    float s = vsum[(b * 128 + t) * 2], ss = vsum[(b * 128 + t) * 2 + 1];
    float mean = s / 9216.f;
    v[t] = (ss - 9216.f * mean * mean) / 9215.f;
    idx[t] = t; __syncthreads();
    for (int o = 64; o > 0; o >>= 1) {
        if (t < o) { if (v[t + o] > v[t]) { v[t] = v[t + o]; idx[t] = idx[t + o]; } }
        __syncthreads();
    }
    if (t == 0) cmax[b] = idx[0];
}

// ---------------- gather (j=1..3): sel16[b3][p][c] bf16, roi[b3][p] ----------------
// 16 px/block, 16 threads per px each owning 8 channels (vectorized s16x8 corners).
__global__ __launch_bounds__(256) void k_gather(const unsigned short* __restrict__ xT, const float* __restrict__ th,
                                                const int* __restrict__ cmax, unsigned short* __restrict__ sel16,
                                                float* __restrict__ roi) {
    int blk = blockIdx.x;
    int bj6 = blk / 576, pblk = blk - bj6 * 576;
    int b = bj6 / 3, j = bj6 - b * 3 + 1;
    int pxr = threadIdx.x >> 4, g = threadIdx.x & 15;
    const float* t6 = th + (b * 4 + j) * 6;
    float T0 = t6[0], T1 = t6[1], T2 = t6[2], T3 = t6[3], T4 = t6[4], T5 = t6[5];
    int cm = cmax[b];
    const unsigned short* base = xT + (size_t)(b * 4 + j) * HW * CC;
    const unsigned short* ebase = xT + (size_t)(b * 4) * HW * CC;
    int p = pblk * 16 + pxr;
    int h = p / 96, w = p - h * 96;
    float X = -1.f + (2.f / 95.f) * (float)w, Y = -1.f + (2.f / 95.f) * (float)h;
    float gx = T0 * X + T1 * Y + T2;
    float gy = T3 * X + T4 * Y + T5;
    float px = (gx + 1.f) * 47.5f, py = (gy + 1.f) * 47.5f;
    float x0f = floorf(px), y0f = floorf(py);
    float wx = px - x0f, wy = py - y0f;
    int x0 = (int)x0f, y0 = (int)y0f, x1 = x0 + 1, y1 = y0 + 1;
    float w00 = (1.f - wx) * (1.f - wy), w10 = wx * (1.f - wy);
    float w01 = (1.f - wx) * wy, w11 = wx * wy;
    bool vx0 = (x0 >= 0) && (x0 <= 95), vx1 = (x1 >= 0) && (x1 <= 95);
    bool vy0 = (y0 >= 0) && (y0 <= 95), vy1 = (y1 >= 0) && (y1 <= 95);
    float f00 = (vx0 && vy0) ? w00 : 0.f, f10 = (vx1 && vy0) ? w10 : 0.f;
    float f01 = (vx0 && vy1) ? w01 : 0.f, f11 = (vx1 && vy1) ? w11 : 0.f;
    int xc0 = min(max(x0, 0), 95), xc1 = min(max(x1, 0), 95);
    int yc0 = min(max(y0, 0), 95), yc1 = min(max(y1, 0), 95);
    s16x8 v00 = *(const s16x8*)(base + (size_t)((95 - xc0) * 96 + yc0) * CC + g * 8);
    s16x8 v10 = *(const s16x8*)(base + (size_t)((95 - xc1) * 96 + yc0) * CC + g * 8);
    s16x8 v01 = *(const s16x8*)(base + (size_t)((95 - xc0) * 96 + yc1) * CC + g * 8);
    s16x8 v11 = *(const s16x8*)(base + (size_t)((95 - xc1) * 96 + yc1) * CC + g * 8);
    s16x8 ve  = *(const s16x8*)(ebase + (size_t)((95 - w) * 96 + h) * CC + g * 8);
    s16x8 sv;
    #pragma unroll
    for (int e = 0; e < 8; e++) {
        float nb = f00 * bf2f((unsigned short)v00[e]) + f10 * bf2f((unsigned short)v10[e])
                 + f01 * bf2f((unsigned short)v01[e]) + f11 * bf2f((unsigned short)v11[e]);
        int c = g * 8 + e;
        unsigned short r = (b == 0) ? f2bf(nb) : ((c == cm) ? f2bf(nb) : (unsigned short)ve[e]);
        sv[e] = (short)r;
    }
    *(s16x8*)(sel16 + ((size_t)bj6 * HW + p) * CC + g * 8) = sv;
    if (g == 0) roi[(size_t)bj6 * HW + p] = f00 + f10 + f01 + f11;
}

// ---------------- mega-fused, wave-per-source: MLP -> softmax -> combine -> final GEMM ----------------
// 256 thr (4 waves), 32 px/block, 576 blocks. Wave w handles source j=w end-to-end.
// LDS 67840 B -> 2 blocks/CU. Exactly 2 __syncthreads per block.
__global__ __launch_bounds__(256) void k_fused(
    const unsigned short* __restrict__ xT, const unsigned short* __restrict__ sel16,
    const float* __restrict__ roiB,
    const unsigned short* __restrict__ w1b, const unsigned short* __restrict__ w2b,
    const unsigned short* __restrict__ mwb,
    const float* __restrict__ b1, const float* __restrict__ s1, const float* __restrict__ t1,
    const float* __restrict__ b2, const float* __restrict__ s2, const float* __restrict__ t2,
    const float* __restrict__ w3, const float* __restrict__ b3, const float* __restrict__ s3,
    const float* __restrict__ t3, const float* __restrict__ w4, const float* __restrict__ b4,
    const float* __restrict__ mb, float* __restrict__ out) {
    // layout: tiles j*8192 (j=0 ego); wave scratch 32768 + w*8192 (l1T bf16 [32][256B],
    //         later overlaid by l2s f32 [32][36]); lgs @65536; rois @66048; w3s[8][36] @66560; cs3 @67712.
    __shared__ __align__(16) unsigned char sm[67840];
    float* lgs  = (float*)(sm + 65536);
    float* rois = (float*)(sm + 66048);
    float* w3s  = (float*)(sm + 66560);
    float* cs3  = (float*)(sm + 67712);
    int t = threadIdx.x;
    int blk = blockIdx.x;
    int b = blk / 288, pt = blk - b * 288;
    int p0 = pt * 32;
    // ---- stage: ego tile (slot 0) + 3 sel tiles, swizzled ----
    const unsigned short* egb = xT + (size_t)(b * 4) * HW * CC;
    #pragma unroll
    for (int it = 0; it < 2; it++) {
        int u = it * 256 + t;
        int px = u >> 4, g = u & 15;
        int p = p0 + px;
        int h = p / 96, w = p - h * 96;
        s16x8 v = *(const s16x8*)(egb + (size_t)((95 - w) * 96 + h) * CC + g * 8);
        *(s16x8*)(sm + px * 256 + ((g * 16) ^ ((px & 7) << 4))) = v;
    }
    #pragma unroll
    for (int j = 1; j < 4; j++) {
        const unsigned short* sp = sel16 + ((size_t)(b * 3 + j - 1) * HW + p0) * CC;
        #pragma unroll
        for (int it = 0; it < 2; it++) {
            int u = it * 256 + t;
            int px = u >> 4, g = u & 15;
            s16x8 v = *(const s16x8*)(sp + px * 128 + g * 8);
            *(s16x8*)(sm + j * 8192 + px * 256 + ((g * 16) ^ ((px & 7) << 4))) = v;
        }
    }
    if (t < 128) {
        int j = t >> 5, px = t & 31;
        rois[j * 32 + px] = (j == 0) ? 1.f : roiB[(size_t)(b * 3 + j - 1) * HW + p0 + px];
    }
    { int o = t >> 5, k = t & 31; w3s[o * 36 + k] = w3[o * 32 + k]; }
    if (t < 8) { cs3[t] = b3[t]; cs3[8 + t] = s3[t]; cs3[16 + t] = t3[t]; cs3[24 + t] = w4[t]; }
    int lane = t & 63, w_ = t >> 6, l15 = lane & 15, l4 = lane >> 4;
    unsigned char* scratch = sm + 32768 + w_ * 8192;
    __syncthreads();   // barrier 1
    // ---- GEMM1 (source j=w_): C[32px][128] = [sel_j || ego][32][256] @ W1^T ----
    f32x4 acc[2][8];
    #pragma unroll
    for (int mt = 0; mt < 2; mt++)
        #pragma unroll
        for (int nt = 0; nt < 8; nt++) acc[mt][nt] = f32x4{0.f, 0.f, 0.f, 0.f};
    const unsigned char* tj = sm + w_ * 8192;
    #pragma unroll
    for (int kt = 0; kt < 8; kt++) {
        const unsigned char* asrc = (kt < 4) ? tj : sm;   // cols 128..255 = ego tile
        int kb = (kt & 3) * 64 + l4 * 16;
        s16x8 af[2];
        #pragma unroll
        for (int mt = 0; mt < 2; mt++)
            af[mt] = *(const s16x8*)(asrc + (mt * 16 + l15) * 256 + (kb ^ ((l15 & 7) << 4)));
        #pragma unroll
        for (int nt = 0; nt < 8; nt++) {
            s16x8 bf = *(const s16x8*)(w1b + (size_t)(nt * 16 + l15) * 256 + kt * 32 + l4 * 8);
            #pragma unroll
            for (int mt = 0; mt < 2; mt++)
                acc[mt][nt] = __builtin_amdgcn_mfma_f32_16x16x32_bf16(af[mt], bf, acc[mt][nt], 0, 0, 0);
        }
    }
    // ---- epilogue1: affine+relu -> wave-private l1T bf16 [32][128] swizzled ----
    #pragma unroll
    for (int nt = 0; nt < 8; nt++) {
        int o = nt * 16 + l15;
        float bb = b1[o], sv = s1[o], tv = t1[o];
        #pragma unroll
        for (int mt = 0; mt < 2; mt++) {
            #pragma unroll
            for (int r = 0; r < 4; r++) {
                int px = mt * 16 + l4 * 4 + r;
                float v = fmaxf((acc[mt][nt][r] + bb) * sv + tv, 0.f);
                *(unsigned short*)(scratch + px * 256 + ((2 * o) ^ ((px & 7) << 4))) = f2bf(v);
            }
        }
    }
    asm volatile("s_waitcnt lgkmcnt(0)" ::: "memory");
    // ---- GEMM2: C[32px][32] = L1[32][128] @ W2^T (whole wave) ----
    f32x4 acc2[2][2];
    #pragma unroll
    for (int mt = 0; mt < 2; mt++)
        #pragma unroll
        for (int nt = 0; nt < 2; nt++) acc2[mt][nt] = f32x4{0.f, 0.f, 0.f, 0.f};
    #pragma unroll
    for (int kt = 0; kt < 4; kt++) {
        s16x8 af2[2];
        #pragma unroll
        for (int mt = 0; mt < 2; mt++) {
            int px = mt * 16 + l15;
            af2[mt] = *(const s16x8*)(scratch + px * 256 + ((2 * (kt * 32 + l4 * 8)) ^ ((px & 7) << 4)));
        }
        #pragma unroll
        for (int nt = 0; nt < 2; nt++) {
            s16x8 bf = *(const s16x8*)(w2b + (size_t)(nt * 16 + l15) * 128 + kt * 32 + l4 * 8);
            #pragma unroll
            for (int mt = 0; mt < 2; mt++)
                acc2[mt][nt] = __builtin_amdgcn_mfma_f32_16x16x32_bf16(af2[mt], bf, acc2[mt][nt], 0, 0, 0);
        }
    }
    asm volatile("s_waitcnt lgkmcnt(0)" ::: "memory");
    // ---- epilogue2: affine+relu -> l2s f32 [32][36] (overlays scratch; same wave only) ----
    float* l2s = (float*)scratch;
    #pragma unroll
    for (int nt = 0; nt < 2; nt++) {
        int o = nt * 16 + l15;
        float bb = b2[o], sv = s2[o], tv = t2[o];
        #pragma unroll
        for (int mt = 0; mt < 2; mt++) {
            #pragma unroll
            for (int r = 0; r < 4; r++) {
                int px = mt * 16 + l4 * 4 + r;
                l2s[px * 36 + o] = fmaxf((acc2[mt][nt][r] + bb) * sv + tv, 0.f);
            }
        }
    }
    asm volatile("s_waitcnt lgkmcnt(0)" ::: "memory");
    // ---- layers 3+4 fp32 (lanes 0..31 of EVERY wave, concurrent across sources) ----
    if (lane < 32) {
        int px = lane;
        f32x4 xv[8];
        #pragma unroll
        for (int kc = 0; kc < 8; kc++) xv[kc] = *(const f32x4*)(l2s + px * 36 + kc * 4);
        float lg = b4[0];
        #pragma unroll
        for (int o = 0; o < 8; o++) {
            float a = 0.f;
            #pragma unroll
            for (int kc = 0; kc < 8; kc++) {
                f32x4 wv = *(const f32x4*)(w3s + o * 36 + kc * 4);
                a += xv[kc][0] * wv[0] + xv[kc][1] * wv[1] + xv[kc][2] * wv[2] + xv[kc][3] * wv[3];
            }
            float l3 = fmaxf((a + cs3[o]) * cs3[8 + o] + cs3[16 + o], 0.f);
            lg += cs3[24 + o] * l3;
        }
        lgs[w_ * 32 + px] = fmaxf(lg, 0.f);
    }
    __syncthreads();   // barrier 2
    // ---- softmax weights (per lane, for its A-frag rows px = mt*16+l15) ----
    float wgt[2][4];
    #pragma unroll
    for (int mt = 0; mt < 2; mt++) {
        int px = mt * 16 + l15;
        float rr[4], lg[4];
        #pragma unroll
        for (int j = 0; j < 4; j++) { rr[j] = rois[j * 32 + px]; lg[j] = lgs[j * 32 + px]; }
        float m = -1e30f;
        #pragma unroll
        for (int j = 0; j < 4; j++) if (rr[j] != 0.f && lg[j] > m) m = lg[j];
        float e[4], se = 0.f;
        #pragma unroll
        for (int j = 0; j < 4; j++) { e[j] = (rr[j] != 0.f) ? expf(lg[j] - m) : 0.f; se += e[j]; }
        float inv = 1.f / se;
        #pragma unroll
        for (int j = 0; j < 4; j++) wgt[mt][j] = e[j] * inv * rr[j];
    }
    // ---- combine (in-register, from LDS tiles) + final GEMM; wave owns out cols w_*32..+31 ----
    f32x4 acc3[2][2];
    #pragma unroll
    for (int mt = 0; mt < 2; mt++)
        #pragma unroll
        for (int nt = 0; nt < 2; nt++) acc3[mt][nt] = f32x4{0.f, 0.f, 0.f, 0.f};
    #pragma unroll
    for (int kt = 0; kt < 4; kt++) {
        s16x8 bfr[2];
        #pragma unroll
        for (int nt = 0; nt < 2; nt++)
            bfr[nt] = *(const s16x8*)(mwb + (size_t)(w_ * 32 + nt * 16 + l15) * 128 + kt * 32 + l4 * 8);
        #pragma unroll
        for (int mt = 0; mt < 2; mt++) {
            int px = mt * 16 + l15;
            int byo = (kt * 64 + l4 * 16) ^ ((l15 & 7) << 4);
            float accv[8];
            #pragma unroll
            for (int e = 0; e < 8; e++) accv[e] = 0.f;
            #pragma unroll
            for (int j = 0; j < 4; j++) {
                s16x8 v = *(const s16x8*)(sm + j * 8192 + px * 256 + byo);
                float wj = wgt[mt][j];
                #pragma unroll
                for (int e = 0; e < 8; e++) accv[e] += wj * bf2f((unsigned short)v[e]);
            }
            s16x8 af;
            #pragma unroll
            for (int e = 0; e < 8; e++) af[e] = (short)f2bf(accv[e]);
            #pragma unroll
            for (int nt = 0; nt < 2; nt++)
                acc3[mt][nt] = __builtin_amdgcn_mfma_f32_16x16x32_bf16(af, bfr[nt], acc3[mt][nt], 0, 0, 0);
        }
    }
    float mbv[2];
    #pragma unroll
    for (int nt = 0; nt < 2; nt++) mbv[nt] = mb[w_ * 32 + nt * 16 + l15];
    #pragma unroll
    for (int mt = 0; mt < 2; mt++) {
        #pragma unroll
        for (int nt = 0; nt < 2; nt++) {
            #pragma unroll
            for (int r = 0; r < 4; r++) {
                int px = mt * 16 + l4 * 4 + r;
                int p = p0 + px;
                int h = p / 96, ww = p - h * 96;
                out[(((size_t)b * 96 + (95 - ww)) * 96 + h) * CC + w_ * 32 + nt * 16 + l15] = acc3[mt][nt][r] + mbv[nt];
            }
        }
    }
}

extern "C" void kernel_launch(void* const* d_in, const int* in_sizes, int n_in,
                              void* d_out, int out_size, void* d_ws, size_t ws_size,
                              hipStream_t stream) {
    const float* x  = (const float*)d_in[0];
    const float* P  = (const float*)d_in[2];
    const float* w1 = (const float*)d_in[3];
    const float* b1 = (const float*)d_in[4];
    const float* s1 = (const float*)d_in[5];
    const float* t1 = (const float*)d_in[6];
    const float* w2 = (const float*)d_in[7];
    const float* b2 = (const float*)d_in[8];
    const float* s2 = (const float*)d_in[9];
    const float* t2 = (const float*)d_in[10];
    const float* w3 = (const float*)d_in[11];
    const float* b3 = (const float*)d_in[12];
    const float* s3 = (const float*)d_in[13];
    const float* t3 = (const float*)d_in[14];
    const float* w4 = (const float*)d_in[15];
    const float* b4 = (const float*)d_in[16];
    const float* mw = (const float*)d_in[17];
    const float* mb = (const float*)d_in[18];
    float* out = (float*)d_out;

    float* ws = (float*)d_ws;
    float* TH   = ws;                                     // 48 (pad 64)
    float* VSUM = ws + 64;                                // [2][128][2] = 512
    int*   CMX  = (int*)(ws + 576);                       // 2 (pad to 1024)
    unsigned short* XT    = (unsigned short*)(ws + 1024); // 8*HW*128 = 9437184 bf16
    unsigned short* SEL16 = XT + 9437184;                 // 6*HW*128 = 7077888 bf16
    float* ROI = (float*)(SEL16 + 7077888);               // 6*HW = 55296
    unsigned short* W1B = (unsigned short*)(ROI + 55296); // 32768
    unsigned short* W2B = W1B + 32768;                    // 4096
    unsigned short* MWB = W2B + 4096;                     // 16384

    hipMemsetAsync(VSUM, 0, 512 * sizeof(float), stream);
    k_prep<<<16, 256, 0, stream>>>(P, w1, w2, mw, TH, W1B, W2B, MWB);
    k_transpose<<<768, 256, 0, stream>>>(x, XT, VSUM);
    k_argmax<<<2, 128, 0, stream>>>(VSUM, CMX);
    k_gather<<<3456, 256, 0, stream>>>(XT, TH, CMX, SEL16, ROI);
    k_fused<<<576, 256, 0, stream>>>(XT, SEL16, ROI, W1B, W2B, MWB,
                                     b1, s1, t1, b2, s2, t2, w3, b3, s3, t3, w4, b4, mb, out);
}